// Round 15
// baseline (34556.308 us; speedup 1.0000x reference)
//
#include <hip/hip_runtime.h>
#include <math.h>

#define HDIM 1024
#define NTAG 256
#define BSZ 128
#define TLEN 50
#define G3 3072
#define NBLK 256
#define NGRP 8

typedef unsigned long long u64;
typedef unsigned short u16;

constexpr u64 GX_F  = (u64)TLEN*G3*BSZ;
constexpr u64 SEQ_F = (u64)TLEN*HDIM*BSZ;
constexpr u64 F_GX  = 0;
constexpr u64 F_OF0 = F_GX + GX_F;
constexpr u64 F_OB0 = F_OF0 + SEQ_F;
constexpr u64 F_ENC = F_OB0 + SEQ_F;
constexpr u64 F_NLL = F_ENC + SEQ_F;
constexpr u64 F_H1T = F_NLL + (u64)TLEN*BSZ;        // u16 [128][1024]
constexpr u64 F_CWB = F_H1T + 65536;                // u16 1024x2048
constexpr u64 F_OWB = F_CWB + 1048576;              // u16 256x1024
constexpr u64 F_ETB = F_OWB + 131072;               // u16 [128][50][1024]
constexpr u64 SHU   = 65536;                        // one u16 [1024][128] state
constexpr u64 F_T0  = F_ETB + 3276800;
constexpr u64 F_T1  = F_T0 + SHU;
constexpr u64 F_HF16= F_T1 + SHU;                   // L0 fwd final (decoder h0 init)
constexpr u64 F_HB16= F_HF16 + SHU;                 // L0 bwd final (decoder h1 init)
constexpr u64 F_SH0A= F_HB16 + SHU;
constexpr u64 F_SH0B= F_SH0A + SHU;
constexpr u64 F_SH1A= F_SH0B + SHU;
constexpr u64 F_SH1B= F_SH1A + SHU;
constexpr u64 F_SCTX= F_SH1B + SHU;
constexpr u64 F_CCT = F_SCTX + SHU;                 // u16 [128][1024]
constexpr u64 POOL_F= F_CCT + SHU;

__device__ __align__(256) float g_pool[POOL_F];
__device__ unsigned g_grp[NGRP*32];
__device__ unsigned g_root;
__device__ unsigned g_gen;

__device__ __forceinline__ float sigmf(float x){ return 1.f/(1.f+__expf(-x)); }
__device__ __forceinline__ u16 f2b(float x){
  unsigned u = __float_as_uint(x);
  u += 0x7fffu + ((u>>16)&1u);
  return (u16)(u>>16);
}
__device__ __forceinline__ float b2f(u16 s){ return __uint_as_float(((unsigned)s)<<16); }
__device__ __forceinline__ float b2f_lo(unsigned p){ return __uint_as_float(p<<16); }
__device__ __forceinline__ float b2f_hi(unsigned p){ return __uint_as_float(p & 0xffff0000u); }

__device__ __forceinline__ void grid_sync(){
  __syncthreads();
  if (threadIdx.x == 0){
    __threadfence();
    const int g = blockIdx.x & (NGRP-1);
    unsigned gen = __hip_atomic_load(&g_gen, __ATOMIC_RELAXED, __HIP_MEMORY_SCOPE_AGENT);
    unsigned old = __hip_atomic_fetch_add(&g_grp[g*32], 1u, __ATOMIC_ACQ_REL, __HIP_MEMORY_SCOPE_AGENT);
    if (old == (NBLK/NGRP)-1){
      unsigned ro = __hip_atomic_fetch_add(&g_root, 1u, __ATOMIC_ACQ_REL, __HIP_MEMORY_SCOPE_AGENT);
      if (ro == NGRP-1){
        __hip_atomic_store(&g_root, 0u, __ATOMIC_RELAXED, __HIP_MEMORY_SCOPE_AGENT);
        #pragma unroll
        for (int i=0;i<NGRP;++i)
          __hip_atomic_store(&g_grp[i*32], 0u, __ATOMIC_RELAXED, __HIP_MEMORY_SCOPE_AGENT);
        __hip_atomic_fetch_add(&g_gen, 1u, __ATOMIC_ACQ_REL, __HIP_MEMORY_SCOPE_AGENT);
      } else {
        while (__hip_atomic_load(&g_gen, __ATOMIC_ACQUIRE, __HIP_MEMORY_SCOPE_AGENT) == gen)
          __builtin_amdgcn_s_sleep(2);
      }
    } else {
      while (__hip_atomic_load(&g_gen, __ATOMIC_ACQUIRE, __HIP_MEMORY_SCOPE_AGENT) == gen)
        __builtin_amdgcn_s_sleep(2);
    }
    __threadfence();
  }
  __syncthreads();
}

// 12-row GEMM: bf16 W in LDS padded [k][16], bf16 A [k][b]; 8 waves x KPW=128; 16-deep prefetch
__device__ __forceinline__ void ggemm12u(const u16* __restrict__ wl,
                                         const u16* __restrict__ aT,
                                         float (&acc)[12][2], int tid)
{
  const int w = tid>>6, l2 = (tid&63)*2;
  #pragma unroll
  for (int r=0;r<12;++r){ acc[r][0]=0.f; acc[r][1]=0.f; }
  const int k0 = w*128;
  const u16* ap = aT + (u64)k0*BSZ + l2;
  const u16* wp = wl + k0*16;
  for (int kb=0; kb<128; kb+=16){
    unsigned a[16];
    #pragma unroll
    for (int u=0;u<16;++u) a[u] = *(const unsigned*)(ap + (u64)(kb+u)*BSZ);
    #pragma unroll
    for (int u=0;u<16;++u){
      const uint4 wA = *(const uint4*)(wp + (kb+u)*16);
      const uint4 wB = *(const uint4*)(wp + (kb+u)*16 + 8);
      float wv[12];
      wv[0]=b2f_lo(wA.x); wv[1]=b2f_hi(wA.x);
      wv[2]=b2f_lo(wA.y); wv[3]=b2f_hi(wA.y);
      wv[4]=b2f_lo(wA.z); wv[5]=b2f_hi(wA.z);
      wv[6]=b2f_lo(wA.w); wv[7]=b2f_hi(wA.w);
      wv[8]=b2f_lo(wB.x); wv[9]=b2f_hi(wB.x);
      wv[10]=b2f_lo(wB.y); wv[11]=b2f_hi(wB.y);
      const float ax = b2f_lo(a[u]), ay = b2f_hi(a[u]);
      #pragma unroll
      for (int r=0;r<12;++r){ acc[r][0] += wv[r]*ax; acc[r][1] += wv[r]*ay; }
    }
  }
}

__device__ __forceinline__ void reduce12(const float (&acc)[12][2], float* red, int tid){
  const int w = tid>>6, l2 = (tid&63)*2;
  __syncthreads();
  #pragma unroll
  for (int r=0;r<12;++r){
    red[(u64)(w*12+r)*128 + l2]   = acc[r][0];
    red[(u64)(w*12+r)*128 + l2+1] = acc[r][1];
  }
  __syncthreads();
}

#define AM_ENC 0
#define AM_DEC 1
#define AM_CAT 2

template<int AMODE>
__global__ __launch_bounds__(256)
void gemm_gx(const float* __restrict__ embed,
             u64 a1_f, u64 a2_f,
             const int* __restrict__ ids,
             const float* __restrict__ W,
             const float* __restrict__ bias,
             u64 c_f, int K)
{
  constexpr int TM=128, TN=64, TK=32;
  __shared__ float As[TK][TM+4];
  __shared__ float Ws[TK][TN+4];
  __shared__ int rowid[TM];
  const int t = blockIdx.x;
  const int n0 = blockIdx.y*TN;
  const int tid = threadIdx.x;

  if (AMODE != AM_CAT){
    for (int r=tid; r<TM; r+=256)
      rowid[r] = (AMODE==AM_ENC) ? ids[r*TLEN+t] : ((t==0)?1:ids[r*TLEN+t-1]);
    __syncthreads();
  }

  const int tm = tid>>4, tn = tid&15;
  float acc[8][4];
  #pragma unroll
  for (int i=0;i<8;i++){ acc[i][0]=0.f;acc[i][1]=0.f;acc[i][2]=0.f;acc[i][3]=0.f; }

  for (int k0=0;k0<K;k0+=TK){
    if (AMODE==AM_CAT){
      const int kk = tid>>3, q = tid&7;
      const int kg = k0 + kk;
      const float* src = g_pool + ((kg<HDIM)? (a1_f + ((u64)t*HDIM + kg)*BSZ)
                                            : (a2_f + ((u64)t*HDIM + (kg-HDIM))*BSZ)) + q*16;
      float* d = &As[kk][q*16];
      float4 v0=*(const float4*)(src+0), v1=*(const float4*)(src+4);
      float4 v2=*(const float4*)(src+8), v3=*(const float4*)(src+12);
      *(float4*)(d+0)=v0; *(float4*)(d+4)=v1; *(float4*)(d+8)=v2; *(float4*)(d+12)=v3;
    } else {
      #pragma unroll
      for (int l=tid; l<TM*TK; l+=256){
        int r=l>>5, k=l&31;
        As[k][r] = embed[(u64)rowid[r]*HDIM + k0 + k];
      }
    }
    #pragma unroll
    for (int l=tid; l<TN*TK; l+=256){
      int n=l>>5, k=l&31;
      Ws[k][n] = W[(u64)(n0+n)*K + k0 + k];
    }
    __syncthreads();
    #pragma unroll 8
    for (int kk=0;kk<TK;kk++){
      float4 a0 = *(const float4*)&As[kk][tm*8];
      float4 a1 = *(const float4*)&As[kk][tm*8+4];
      float4 w  = *(const float4*)&Ws[kk][tn*4];
      float av[8]={a0.x,a0.y,a0.z,a0.w,a1.x,a1.y,a1.z,a1.w};
      float wv[4]={w.x,w.y,w.z,w.w};
      #pragma unroll
      for (int i=0;i<8;i++){
        #pragma unroll
        for (int jj=0;jj<4;jj++) acc[i][jj] += av[i]*wv[jj];
      }
    }
    __syncthreads();
  }

  float bv[4];
  #pragma unroll
  for (int jj=0;jj<4;jj++) bv[jj] = bias[n0+tn*4+jj];
  float* C = g_pool + c_f;
  for (int half=0; half<2; ++half){
    if ((tn>>3)==half){
      #pragma unroll
      for (int i=0;i<8;i++)
        #pragma unroll
        for (int jj=0;jj<4;jj++)
          As[(tn&7)*4+jj][tm*8+i] = acc[i][jj]+bv[jj];
    }
    __syncthreads();
    {
      const int nn = tid>>3, q = tid&7;
      float* dst = C + ((u64)t*G3 + n0 + half*32 + nn)*BSZ + q*16;
      const float* srow = &As[nn][q*16];
      float4 v0=*(const float4*)(srow+0), v1=*(const float4*)(srow+4);
      float4 v2=*(const float4*)(srow+8), v3=*(const float4*)(srow+12);
      *(float4*)(dst+0)=v0; *(float4*)(dst+4)=v1; *(float4*)(dst+8)=v2; *(float4*)(dst+12)=v3;
    }
    __syncthreads();
  }
}

// persistent masked GRU scan: bf16 h states, padded bf16 LDS weights, 1 barrier/step
template<bool BWD, bool ACCUM>
__global__ __launch_bounds__(512)
void scan_kernel(u64 gx_f, u64 p0_f, u64 p1_f,
                 const float* __restrict__ whh, const float* __restrict__ bhh,
                 const int* __restrict__ lengths, u64 out_f)
{
  __shared__ u16 wl[HDIM*16];       // 32 KB
  __shared__ float red[8*12*128];   // 48 KB
  const int bid = blockIdx.x, tid = threadIdx.x;
  const int j0 = bid*4;
  #pragma unroll
  for (int r=0;r<12;++r){
    const int row = (r>>2)*HDIM + j0 + (r&3);
    for (int k=tid;k<HDIM;k+=512) wl[k*16+r] = f2b(whh[(u64)row*HDIM + k]);
  }
  __syncthreads();

  const int jl = tid>>7, bb = tid&127;
  const int jg = j0 + jl;
  for (int s=0; s<TLEN; ++s){
    const int t = BWD ? (TLEN-1-s) : s;
    const u16* rd16 = (const u16*)(g_pool + ((s&1)? p0_f : p1_f));
    u16*       wr16 = (u16*)(g_pool + ((s&1)? p1_f : p0_f));
    if (s>0){
      float acc[12][2];
      ggemm12u(wl, rd16, acc, tid);
      reduce12(acc, red, tid);
    }
    const float* gxb = g_pool + gx_f + (u64)t*G3*BSZ;
    {
      const int len = lengths[bb];
      const bool m = (t < len);
      float gh0=0.f, gh1=0.f, gh2=0.f;
      if (s>0){
        #pragma unroll
        for (int w2=0;w2<8;++w2){
          gh0 += red[(u64)(w2*12 + jl)*128 + bb];
          gh1 += red[(u64)(w2*12 + 4 + jl)*128 + bb];
          gh2 += red[(u64)(w2*12 + 8 + jl)*128 + bb];
        }
      }
      const float xr = gxb[(u64)jg*BSZ + bb];
      const float xz = gxb[(u64)(HDIM+jg)*BSZ + bb];
      const float xn = gxb[(u64)(2*HDIM+jg)*BSZ + bb];
      const float hp = (s>0)? b2f(rd16[(u64)jg*BSZ + bb]) : 0.f;
      const float r = sigmf(xr + gh0 + bhh[jg]);
      const float z = sigmf(xz + gh1 + bhh[HDIM+jg]);
      const float n = tanhf(xn + r*(gh2 + bhh[2*HDIM+jg]));
      const float hv = (1.f-z)*n + z*hp;
      wr16[(u64)jg*BSZ + bb] = f2b(m ? hv : hp);
      const u64 oidx = out_f + ((u64)t*HDIM + jg)*BSZ + bb;
      if (ACCUM){ if (m) g_pool[oidx] += hv; }
      else g_pool[oidx] = m ? hv : 0.f;
    }
    grid_sync();
  }
}

// one-time converters
__global__ __launch_bounds__(256)
void conv_w(const float* __restrict__ cw, const float* __restrict__ ow){
  u16* cwb = (u16*)(g_pool + F_CWB);
  u16* owb = (u16*)(g_pool + F_OWB);
  const u64 n1 = (u64)HDIM*2*HDIM;
  const u64 n2 = (u64)NTAG*HDIM;
  for (u64 i = (u64)blockIdx.x*256+threadIdx.x; i<n1; i += (u64)gridDim.x*256) cwb[i]=f2b(cw[i]);
  for (u64 i = (u64)blockIdx.x*256+threadIdx.x; i<n2; i += (u64)gridDim.x*256) owb[i]=f2b(ow[i]);
}
__global__ __launch_bounds__(256)
void enc_t(){
  const int t = blockIdx.x, kc = blockIdx.y;
  u16* etb = (u16*)(g_pool + F_ETB);
  for (int it=threadIdx.x; it<128*128; it+=256){
    const int kl = it>>7, b = it&127;
    const int k = kc*128 + kl;
    etb[(u64)b*(TLEN*HDIM) + (u64)t*HDIM + k] = f2b(g_pool[F_ENC + ((u64)t*HDIM+k)*BSZ + b]);
  }
}

// persistent decoder: 4 grid barriers per step
__global__ __launch_bounds__(512)
void decoder_kernel(const float* __restrict__ whh0, const float* __restrict__ bhh0,
                    const float* __restrict__ wih1, const float* __restrict__ bih1,
                    const float* __restrict__ whh1, const float* __restrict__ bhh1,
                    const float* __restrict__ cb, const float* __restrict__ ob,
                    const int* __restrict__ tag_ids, const int* __restrict__ lengths,
                    float* __restrict__ dout)
{
  __shared__ u16 wl0[HDIM*16];      // 32 KB
  __shared__ u16 wl1[HDIM*16];
  __shared__ u16 wl2[HDIM*16];
  __shared__ float red[8*12*128];   // 48 KB
  const int bid = blockIdx.x, tid = threadIdx.x;
  const int j0 = bid*4;
  const int w = tid>>6, l = tid&63;
  const int jl = tid>>7, bb = tid&127;
  const int jg = j0 + jl;

  #pragma unroll
  for (int r=0;r<12;++r){
    const int gr = (r>>2)*HDIM + j0 + (r&3);
    for (int k=tid;k<HDIM;k+=512){
      wl0[k*16+r] = f2b(whh0[(u64)gr*HDIM + k]);
      wl1[k*16+r] = f2b(wih1[(u64)gr*HDIM + k]);
      wl2[k*16+r] = f2b(whh1[(u64)gr*HDIM + k]);
    }
  }
  __syncthreads();

  u16* h1t = (u16*)(g_pool + F_H1T);
  const u16* etb = (const u16*)(g_pool + F_ETB);
  const u16* cwb = (const u16*)(g_pool + F_CWB);
  const u16* owb = (const u16*)(g_pool + F_OWB);
  u16* sctx = (u16*)(g_pool + F_SCTX);
  u16* cct  = (u16*)(g_pool + F_CCT);

  for (int t=0; t<TLEN; ++t){
    const u16* h0c = (const u16*)(g_pool + ((t==0)? F_HF16 : ((t&1)? F_SH0A : F_SH0B)));
    u16*       h0n = (u16*)(g_pool + ((t&1)? F_SH0B : F_SH0A));
    const u16* h1c = (const u16*)(g_pool + ((t==0)? F_HB16 : ((t&1)? F_SH1A : F_SH1B)));
    u16*       h1n = (u16*)(g_pool + ((t&1)? F_SH1B : F_SH1A));

    // ---- P1: layer-0 GRU ----
    {
      float acc[12][2];
      ggemm12u(wl0, h0c, acc, tid);
      reduce12(acc, red, tid);
      const float* gxb = g_pool + F_GX + (u64)t*G3*BSZ;
      float gh0=0.f, gh1=0.f, gh2=0.f;
      #pragma unroll
      for (int w2=0;w2<8;++w2){
        gh0 += red[(u64)(w2*12 + jl)*128 + bb];
        gh1 += red[(u64)(w2*12 + 4 + jl)*128 + bb];
        gh2 += red[(u64)(w2*12 + 8 + jl)*128 + bb];
      }
      const float xr = gxb[(u64)jg*BSZ+bb], xz = gxb[(u64)(HDIM+jg)*BSZ+bb], xn = gxb[(u64)(2*HDIM+jg)*BSZ+bb];
      const float hp = b2f(h0c[(u64)jg*BSZ + bb]);
      const float r = sigmf(xr + gh0 + bhh0[jg]);
      const float z = sigmf(xz + gh1 + bhh0[HDIM+jg]);
      const float n = tanhf(xn + r*(gh2 + bhh0[2*HDIM+jg]));
      h0n[(u64)jg*BSZ + bb] = f2b((1.f-z)*n + z*hp);
    }
    grid_sync();   // b1

    // ---- P2: layer-1 GRU ----
    {
      float acc[12][2];
      float aX[3], aH[3];
      ggemm12u(wl1, h0n, acc, tid);
      reduce12(acc, red, tid);
      #pragma unroll
      for (int g=0;g<3;++g){
        float s=0.f;
        #pragma unroll
        for (int w2=0;w2<8;++w2) s += red[(u64)(w2*12 + g*4 + jl)*128 + bb];
        aX[g] = s;
      }
      ggemm12u(wl2, h1c, acc, tid);
      reduce12(acc, red, tid);
      #pragma unroll
      for (int g=0;g<3;++g){
        float s=0.f;
        #pragma unroll
        for (int w2=0;w2<8;++w2) s += red[(u64)(w2*12 + g*4 + jl)*128 + bb];
        aH[g] = s;
      }
      const float hp = b2f(h1c[(u64)jg*BSZ + bb]);
      const float r = sigmf(aX[0] + bih1[jg] + aH[0] + bhh1[jg]);
      const float z = sigmf(aX[1] + bih1[HDIM+jg] + aH[1] + bhh1[HDIM+jg]);
      const float n = tanhf(aX[2] + bih1[2*HDIM+jg] + r*(aH[2] + bhh1[2*HDIM+jg]));
      const float hv = (1.f-z)*n + z*hp;
      const u16 hb = f2b(hv);
      h1n[(u64)jg*BSZ + bb] = hb;
      h1t[(u64)bb*HDIM + jg] = hb;
    }
    grid_sync();   // b2

    // ---- P34: per-b attention (blocks 0..127); scores+softmax+ctx fused ----
    {
      float* hL = red;           // [1024]
      float* sc = red + 1024;    // [64]
      float* aw = red + 1088;    // [64]
      const int b = bid;
      if (bid < 128){
        const u16* hrow = h1t + (u64)b*HDIM;
        const int k = tid*2;
        unsigned hv = *(const unsigned*)(hrow + k);
        hL[k] = b2f_lo(hv); hL[k+1] = b2f_hi(hv);
      }
      __syncthreads();
      if (bid < 128){
        const u16* eb = etb + (u64)b*(TLEN*HDIM);
        for (int tp=w; tp<TLEN; tp+=8){
          const u16* er = eb + (u64)tp*HDIM + l*16;
          uint4 e0 = *(const uint4*)er;
          uint4 e1 = *(const uint4*)(er+8);
          const float* hp = &hL[l*16];
          float s = b2f_lo(e0.x)*hp[0] + b2f_hi(e0.x)*hp[1]
                  + b2f_lo(e0.y)*hp[2] + b2f_hi(e0.y)*hp[3]
                  + b2f_lo(e0.z)*hp[4] + b2f_hi(e0.z)*hp[5]
                  + b2f_lo(e0.w)*hp[6] + b2f_hi(e0.w)*hp[7]
                  + b2f_lo(e1.x)*hp[8] + b2f_hi(e1.x)*hp[9]
                  + b2f_lo(e1.y)*hp[10] + b2f_hi(e1.y)*hp[11]
                  + b2f_lo(e1.z)*hp[12] + b2f_hi(e1.z)*hp[13]
                  + b2f_lo(e1.w)*hp[14] + b2f_hi(e1.w)*hp[15];
          #pragma unroll
          for (int o=32;o;o>>=1) s += __shfl_xor(s, o);
          if (l==0) sc[tp] = s;
        }
      }
      __syncthreads();
      if (bid < 128 && tid < 64){
        float v = (tid<TLEN)? sc[tid] : -1e30f;
        float mx = v;
        #pragma unroll
        for (int o=32;o;o>>=1) mx = fmaxf(mx, __shfl_xor(mx,o));
        float e = (tid<TLEN)? __expf(v-mx) : 0.f;
        float sm = e;
        #pragma unroll
        for (int o=32;o;o>>=1) sm += __shfl_xor(sm,o);
        if (tid < TLEN) aw[tid] = e/sm;
      }
      __syncthreads();
      if (bid < 128){
        const u16* eb = etb + (u64)b*(TLEN*HDIM);
        const int k2 = tid*2;
        float a0=0.f, a1=0.f;
        #pragma unroll 10
        for (int tp=0;tp<TLEN;++tp){
          unsigned e = *(const unsigned*)(eb + (u64)tp*HDIM + k2);
          a0 += aw[tp]*b2f_lo(e); a1 += aw[tp]*b2f_hi(e);
        }
        sctx[(u64)k2*BSZ + b]     = f2b(a0);
        sctx[(u64)(k2+1)*BSZ + b] = f2b(a1);
      }
    }
    grid_sync();   // b3

    // ---- P5: cc (8 waves x K=256 slices; 4 rows each) -> cct[b][n] bf16 ----
    {
      const int l2 = (tid&63)*2;
      const int k0 = w*256;
      const u16* asrc = (k0<1024)? ((const u16*)(g_pool + ((t&1)? F_SH1B : F_SH1A)) + (u64)k0*BSZ)
                                 : (sctx + (u64)(k0-1024)*BSZ);
      const u16* wp0 = cwb + (u64)(j0+0)*2048 + k0;
      const u16* wp1 = cwb + (u64)(j0+1)*2048 + k0;
      const u16* wp2 = cwb + (u64)(j0+2)*2048 + k0;
      const u16* wp3 = cwb + (u64)(j0+3)*2048 + k0;
      float a0[4]={0,0,0,0}, a1v[4]={0,0,0,0};
      for (int kb=0; kb<256; kb+=16){
        unsigned a[16];
        #pragma unroll
        for (int u=0;u<16;++u) a[u] = *(const unsigned*)(asrc + (u64)(kb+u)*BSZ + l2);
        #pragma unroll
        for (int u=0;u<16;++u){
          const float ax = b2f_lo(a[u]), ay = b2f_hi(a[u]);
          const float w0v=b2f(wp0[kb+u]), w1v=b2f(wp1[kb+u]), w2v=b2f(wp2[kb+u]), w3v=b2f(wp3[kb+u]);
          a0[0]+=w0v*ax; a1v[0]+=w0v*ay;
          a0[1]+=w1v*ax; a1v[1]+=w1v*ay;
          a0[2]+=w2v*ax; a1v[2]+=w2v*ay;
          a0[3]+=w3v*ax; a1v[3]+=w3v*ay;
        }
      }
      __syncthreads();
      #pragma unroll
      for (int r=0;r<4;++r){
        red[(u64)(w*4+r)*128 + l2]   = a0[r];
        red[(u64)(w*4+r)*128 + l2+1] = a1v[r];
      }
      __syncthreads();
      {
        const int n2 = j0 + jl;
        float s = cb[n2];
        #pragma unroll
        for (int w2=0;w2<8;++w2) s += red[(u64)(w2*4+jl)*128 + bb];
        cct[(u64)bb*HDIM + n2] = f2b(tanhf(s));
      }
    }
    grid_sync();   // b4

    // ---- P67: per-b logits + softmax + nll (blocks 0..127) ----
    {
      float* ccf = red;          // [1024]
      float* lgL = red + 1024;   // [256]
      float* rp  = red + 1280;   // [256]
      if (bid < 128){
        const int k = tid*2;
        unsigned cv = *(const unsigned*)(cct + (u64)bid*HDIM + k);
        ccf[k] = b2f_lo(cv); ccf[k+1] = b2f_hi(cv);
      }
      __syncthreads();
      if (bid < 128){
        for (int v=w; v<NTAG; v+=8){
          const u16* owr = owb + (u64)v*HDIM + l*16;
          uint4 o0 = *(const uint4*)owr;
          uint4 o1 = *(const uint4*)(owr+8);
          const float* cp = &ccf[l*16];
          float s = b2f_lo(o0.x)*cp[0] + b2f_hi(o0.x)*cp[1]
                  + b2f_lo(o0.y)*cp[2] + b2f_hi(o0.y)*cp[3]
                  + b2f_lo(o0.z)*cp[4] + b2f_hi(o0.z)*cp[5]
                  + b2f_lo(o0.w)*cp[6] + b2f_hi(o0.w)*cp[7]
                  + b2f_lo(o1.x)*cp[8] + b2f_hi(o1.x)*cp[9]
                  + b2f_lo(o1.y)*cp[10] + b2f_hi(o1.y)*cp[11]
                  + b2f_lo(o1.z)*cp[12] + b2f_hi(o1.z)*cp[13]
                  + b2f_lo(o1.w)*cp[14] + b2f_hi(o1.w)*cp[15];
          #pragma unroll
          for (int o=32;o;o>>=1) s += __shfl_xor(s, o);
          if (l==0) lgL[v] = s + ob[v];
        }
      }
      __syncthreads();
      const bool act = (bid < 128) && (tid < 256);
      float lg = 0.f;
      if (act){ lg = lgL[tid]; rp[tid] = lg; }
      __syncthreads();
      for (int o=128;o;o>>=1){ if (bid<128 && tid<o) rp[tid]=fmaxf(rp[tid],rp[tid+o]); __syncthreads(); }
      const float mx = (bid<128)? rp[0] : 0.f;
      __syncthreads();
      if (act) rp[tid] = __expf(lg-mx);
      __syncthreads();
      for (int o=128;o;o>>=1){ if (bid<128 && tid<o) rp[tid]+=rp[tid+o]; __syncthreads(); }
      if (act){
        const float lse = mx + __logf(rp[0]);
        dout[((u64)bid*TLEN + t)*NTAG + tid] = lg;
        if (tid==0){
          const int tag = tag_ids[bid*TLEN + t];
          g_pool[F_NLL + (u64)t*BSZ + bid] = lse - lgL[tag];
        }
      }
    }
    // no trailing barrier: P67 readers of cct finish before any block passes b1(t+1)
  }
  grid_sync();
  // ---- loss ----
  if (bid == 0){
    float ssum = 0.f;
    for (int i=tid; i<TLEN*BSZ; i+=512){
      const int tt = i>>7, b = i&127;
      if (tt < lengths[b]) ssum += g_pool[F_NLL + i];
    }
    red[tid] = ssum; __syncthreads();
    for (int o=256;o;o>>=1){ if (tid<o) red[tid]+=red[tid+o]; __syncthreads(); }
    if (tid==0){
      int den=0;
      for (int b=0;b<BSZ;b++) den += lengths[b];
      dout[(u64)BSZ*TLEN*NTAG] = red[0]/(float)den;
    }
  }
}

extern "C" void kernel_launch(void* const* d_in, const int* in_sizes, int n_in,
                              void* d_out, int out_size, void* d_ws, size_t ws_size,
                              hipStream_t stream)
{
  const float* enc_embed = (const float*)d_in[0];
  const float* e0_wih = (const float*)d_in[1];
  const float* e0_whh = (const float*)d_in[2];
  const float* e0_bih = (const float*)d_in[3];
  const float* e0_bhh = (const float*)d_in[4];
  const float* e1_wih = (const float*)d_in[5];
  const float* e1_whh = (const float*)d_in[6];
  const float* e1_bih = (const float*)d_in[7];
  const float* e1_bhh = (const float*)d_in[8];
  const float* dec_embed = (const float*)d_in[9];
  const float* d_wih = (const float*)d_in[10];
  const float* d_whh = (const float*)d_in[11];
  const float* d_bih = (const float*)d_in[12];
  const float* d_bhh = (const float*)d_in[13];
  const float* concat_w = (const float*)d_in[14];
  const float* concat_b = (const float*)d_in[15];
  const float* out_w = (const float*)d_in[16];
  const float* out_b = (const float*)d_in[17];
  const int* input_ids = (const int*)d_in[18];
  const int* tag_ids  = (const int*)d_in[19];
  const int* lengths  = (const int*)d_in[20];
  float* dout = (float*)d_out;

  const dim3 gxg(TLEN, G3/64);

  gemm_gx<AM_ENC><<<gxg,256,0,stream>>>(enc_embed,0,0,input_ids,e0_wih,e0_bih,F_GX,HDIM);
  scan_kernel<false,false><<<NBLK,512,0,stream>>>(F_GX, F_T0, F_HF16, e0_whh, e0_bhh, lengths, F_OF0);
  gemm_gx<AM_ENC><<<gxg,256,0,stream>>>(enc_embed,0,0,input_ids,
                                        e0_wih+(u64)G3*HDIM, e0_bih+G3, F_GX, HDIM);
  scan_kernel<true,false><<<NBLK,512,0,stream>>>(F_GX, F_T0, F_HB16,
                                        e0_whh+(u64)G3*HDIM, e0_bhh+G3, lengths, F_OB0);
  gemm_gx<AM_CAT><<<gxg,256,0,stream>>>(nullptr, F_OF0, F_OB0, nullptr,
                                        e1_wih, e1_bih, F_GX, 2*HDIM);
  scan_kernel<false,false><<<NBLK,512,0,stream>>>(F_GX, F_T0, F_T1, e1_whh, e1_bhh, lengths, F_ENC);
  gemm_gx<AM_CAT><<<gxg,256,0,stream>>>(nullptr, F_OF0, F_OB0, nullptr,
                                        e1_wih+(u64)G3*2*HDIM, e1_bih+G3, F_GX, 2*HDIM);
  scan_kernel<true,true><<<NBLK,512,0,stream>>>(F_GX, F_T0, F_T1,
                                        e1_whh+(u64)G3*HDIM, e1_bhh+G3, lengths, F_ENC);
  gemm_gx<AM_DEC><<<gxg,256,0,stream>>>(dec_embed,0,0,tag_ids, d_wih, d_bih, F_GX, HDIM);
  conv_w<<<256,256,0,stream>>>(concat_w, out_w);
  enc_t<<<dim3(TLEN,8),256,0,stream>>>();
  decoder_kernel<<<NBLK,512,0,stream>>>(d_whh, d_bhh,
                                        d_wih+(u64)G3*HDIM, d_bih+G3,
                                        d_whh+(u64)G3*HDIM, d_bhh+G3,
                                        concat_b, out_b,
                                        tag_ids, lengths, dout);
}

// Round 16
// 29549.072 us; speedup vs baseline: 1.1695x; 1.1695x over previous
//
#include <hip/hip_runtime.h>
#include <math.h>

#define HDIM 1024
#define NTAG 256
#define BSZ 128
#define TLEN 50
#define G3 3072
#define NBLK 256
#define NGRP 8

typedef unsigned long long u64;
typedef unsigned short u16;

constexpr u64 GX_F  = (u64)TLEN*G3*BSZ;
constexpr u64 SEQ_F = (u64)TLEN*HDIM*BSZ;
constexpr u64 HST_F = (u64)HDIM*BSZ;
constexpr u64 F_GX  = 0;
constexpr u64 F_OF0 = F_GX + GX_F;
constexpr u64 F_OB0 = F_OF0 + SEQ_F;
constexpr u64 F_ENC = F_OB0 + SEQ_F;
constexpr u64 F_T0  = F_ENC + SEQ_F;     // f32 scan ping
constexpr u64 F_T1  = F_T0 + HST_F;      // f32 scan pong
constexpr u64 F_H0F = F_T1 + HST_F;      // f32 L0 fwd final
constexpr u64 F_H0B = F_H0F + HST_F;     // f32 L0 bwd final
constexpr u64 F_NLL = F_H0B + HST_F;
constexpr u64 F_CWB = F_NLL + (u64)TLEN*BSZ;   // u16 1024x2048
constexpr u64 F_OWB = F_CWB + 1048576;         // u16 256x1024
constexpr u64 F_ETB = F_OWB + 131072;          // u16 [128][50][1024]
constexpr u64 SHU   = 65536;
constexpr u64 F_SHI0= F_ETB + 3276800;   // u16 decoder h0 init
constexpr u64 F_SHI1= F_SHI0 + SHU;      // u16 decoder h1 init
constexpr u64 F_SH0A= F_SHI1 + SHU;
constexpr u64 F_SH0B= F_SH0A + SHU;
constexpr u64 F_SH1A= F_SH0B + SHU;
constexpr u64 F_SH1B= F_SH1A + SHU;
constexpr u64 F_SCTXR=F_SH1B + SHU;      // u16 [128][1024] row-major ctx
constexpr u64 F_SCC = F_SCTXR + SHU;     // u16 [1024][128] cc
constexpr u64 POOL_F= F_SCC + SHU;

__device__ __align__(256) float g_pool[POOL_F];
__device__ unsigned g_grp[NGRP*32];
__device__ unsigned g_root;
__device__ unsigned g_gen;

__device__ __forceinline__ float sigmf(float x){ return 1.f/(1.f+__expf(-x)); }
__device__ __forceinline__ u16 f2b(float x){
  unsigned u = __float_as_uint(x);
  u += 0x7fffu + ((u>>16)&1u);
  return (u16)(u>>16);
}
__device__ __forceinline__ float b2f(u16 s){ return __uint_as_float(((unsigned)s)<<16); }
__device__ __forceinline__ float b2f_lo(unsigned p){ return __uint_as_float(p<<16); }
__device__ __forceinline__ float b2f_hi(unsigned p){ return __uint_as_float(p & 0xffff0000u); }

__device__ __forceinline__ void grid_sync(){
  __syncthreads();
  if (threadIdx.x == 0){
    __threadfence();
    const int g = blockIdx.x & (NGRP-1);
    unsigned gen = __hip_atomic_load(&g_gen, __ATOMIC_RELAXED, __HIP_MEMORY_SCOPE_AGENT);
    unsigned old = __hip_atomic_fetch_add(&g_grp[g*32], 1u, __ATOMIC_ACQ_REL, __HIP_MEMORY_SCOPE_AGENT);
    if (old == (NBLK/NGRP)-1){
      unsigned ro = __hip_atomic_fetch_add(&g_root, 1u, __ATOMIC_ACQ_REL, __HIP_MEMORY_SCOPE_AGENT);
      if (ro == NGRP-1){
        __hip_atomic_store(&g_root, 0u, __ATOMIC_RELAXED, __HIP_MEMORY_SCOPE_AGENT);
        #pragma unroll
        for (int i=0;i<NGRP;++i)
          __hip_atomic_store(&g_grp[i*32], 0u, __ATOMIC_RELAXED, __HIP_MEMORY_SCOPE_AGENT);
        __hip_atomic_fetch_add(&g_gen, 1u, __ATOMIC_ACQ_REL, __HIP_MEMORY_SCOPE_AGENT);
      } else {
        while (__hip_atomic_load(&g_gen, __ATOMIC_ACQUIRE, __HIP_MEMORY_SCOPE_AGENT) == gen)
          __builtin_amdgcn_s_sleep(2);
      }
    } else {
      while (__hip_atomic_load(&g_gen, __ATOMIC_ACQUIRE, __HIP_MEMORY_SCOPE_AGENT) == gen)
        __builtin_amdgcn_s_sleep(2);
    }
    __threadfence();
  }
  __syncthreads();
}

// decoder GEMM: bf16 W padded [k][16] in LDS, bf16 A [k][b]; 8 waves x 128k
__device__ __forceinline__ void ggemm12u(const u16* __restrict__ wl,
                                         const u16* __restrict__ aT,
                                         float (&acc)[12][2], int tid)
{
  const int w = tid>>6, l2 = (tid&63)*2;
  #pragma unroll
  for (int r=0;r<12;++r){ acc[r][0]=0.f; acc[r][1]=0.f; }
  const int k0 = w*128;
  const u16* ap = aT + (u64)k0*BSZ + l2;
  const u16* wp = wl + k0*16;
  for (int kb=0; kb<128; kb+=16){
    unsigned a[16];
    #pragma unroll
    for (int u=0;u<16;++u) a[u] = *(const unsigned*)(ap + (u64)(kb+u)*BSZ);
    #pragma unroll
    for (int u=0;u<16;++u){
      const uint4 wA = *(const uint4*)(wp + (kb+u)*16);
      const uint4 wB = *(const uint4*)(wp + (kb+u)*16 + 8);
      float wv[12];
      wv[0]=b2f_lo(wA.x); wv[1]=b2f_hi(wA.x);
      wv[2]=b2f_lo(wA.y); wv[3]=b2f_hi(wA.y);
      wv[4]=b2f_lo(wA.z); wv[5]=b2f_hi(wA.z);
      wv[6]=b2f_lo(wA.w); wv[7]=b2f_hi(wA.w);
      wv[8]=b2f_lo(wB.x); wv[9]=b2f_hi(wB.x);
      wv[10]=b2f_lo(wB.y); wv[11]=b2f_hi(wB.y);
      const float ax = b2f_lo(a[u]), ay = b2f_hi(a[u]);
      #pragma unroll
      for (int r=0;r<12;++r){ acc[r][0] += wv[r]*ax; acc[r][1] += wv[r]*ay; }
    }
  }
}

// scan GEMM (round-14): bf16 W [k][12] LDS, f32 A [k][b]
__device__ __forceinline__ void ggemm12(const u16* __restrict__ wl,
                                        const float* __restrict__ aT,
                                        float (&acc)[12][2], int tid)
{
  const int w = tid>>6, l2 = (tid&63)*2;
  #pragma unroll
  for (int r=0;r<12;++r){ acc[r][0]=0.f; acc[r][1]=0.f; }
  const int k0 = w*128;
  const float* ap = aT + (u64)k0*BSZ + l2;
  const u16* wp = wl + k0*12;
  for (int kb=0; kb<128; kb+=16){
    float2 a[16];
    #pragma unroll
    for (int u=0;u<16;++u) a[u] = *(const float2*)(ap + (u64)(kb+u)*BSZ);
    #pragma unroll
    for (int u=0;u<16;++u){
      const u16* wr = wp + (kb+u)*12;
      #pragma unroll
      for (int r=0;r<12;++r){
        const float wv = b2f(wr[r]);
        acc[r][0] += wv*a[u].x; acc[r][1] += wv*a[u].y;
      }
    }
  }
}

__device__ __forceinline__ void reduce12(const float (&acc)[12][2], float* red, int tid){
  const int w = tid>>6, l2 = (tid&63)*2;
  __syncthreads();
  #pragma unroll
  for (int r=0;r<12;++r){
    red[(u64)(w*12+r)*128 + l2]   = acc[r][0];
    red[(u64)(w*12+r)*128 + l2+1] = acc[r][1];
  }
  __syncthreads();
}

#define AM_ENC 0
#define AM_DEC 1
#define AM_CAT 2

template<int AMODE>
__global__ __launch_bounds__(256)
void gemm_gx(const float* __restrict__ embed,
             u64 a1_f, u64 a2_f,
             const int* __restrict__ ids,
             const float* __restrict__ W,
             const float* __restrict__ bias,
             u64 c_f, int K)
{
  constexpr int TM=128, TN=64, TK=32;
  __shared__ float As[TK][TM+4];
  __shared__ float Ws[TK][TN+4];
  __shared__ int rowid[TM];
  const int t = blockIdx.x;
  const int n0 = blockIdx.y*TN;
  const int tid = threadIdx.x;

  if (AMODE != AM_CAT){
    for (int r=tid; r<TM; r+=256)
      rowid[r] = (AMODE==AM_ENC) ? ids[r*TLEN+t] : ((t==0)?1:ids[r*TLEN+t-1]);
    __syncthreads();
  }

  const int tm = tid>>4, tn = tid&15;
  float acc[8][4];
  #pragma unroll
  for (int i=0;i<8;i++){ acc[i][0]=0.f;acc[i][1]=0.f;acc[i][2]=0.f;acc[i][3]=0.f; }

  for (int k0=0;k0<K;k0+=TK){
    if (AMODE==AM_CAT){
      const int kk = tid>>3, q = tid&7;
      const int kg = k0 + kk;
      const float* src = g_pool + ((kg<HDIM)? (a1_f + ((u64)t*HDIM + kg)*BSZ)
                                            : (a2_f + ((u64)t*HDIM + (kg-HDIM))*BSZ)) + q*16;
      float* d = &As[kk][q*16];
      float4 v0=*(const float4*)(src+0), v1=*(const float4*)(src+4);
      float4 v2=*(const float4*)(src+8), v3=*(const float4*)(src+12);
      *(float4*)(d+0)=v0; *(float4*)(d+4)=v1; *(float4*)(d+8)=v2; *(float4*)(d+12)=v3;
    } else {
      #pragma unroll
      for (int l=tid; l<TM*TK; l+=256){
        int r=l>>5, k=l&31;
        As[k][r] = embed[(u64)rowid[r]*HDIM + k0 + k];
      }
    }
    #pragma unroll
    for (int l=tid; l<TN*TK; l+=256){
      int n=l>>5, k=l&31;
      Ws[k][n] = W[(u64)(n0+n)*K + k0 + k];
    }
    __syncthreads();
    #pragma unroll 8
    for (int kk=0;kk<TK;kk++){
      float4 a0 = *(const float4*)&As[kk][tm*8];
      float4 a1 = *(const float4*)&As[kk][tm*8+4];
      float4 w  = *(const float4*)&Ws[kk][tn*4];
      float av[8]={a0.x,a0.y,a0.z,a0.w,a1.x,a1.y,a1.z,a1.w};
      float wv[4]={w.x,w.y,w.z,w.w};
      #pragma unroll
      for (int i=0;i<8;i++){
        #pragma unroll
        for (int jj=0;jj<4;jj++) acc[i][jj] += av[i]*wv[jj];
      }
    }
    __syncthreads();
  }

  float bv[4];
  #pragma unroll
  for (int jj=0;jj<4;jj++) bv[jj] = bias[n0+tn*4+jj];
  float* C = g_pool + c_f;
  for (int half=0; half<2; ++half){
    if ((tn>>3)==half){
      #pragma unroll
      for (int i=0;i<8;i++)
        #pragma unroll
        for (int jj=0;jj<4;jj++)
          As[(tn&7)*4+jj][tm*8+i] = acc[i][jj]+bv[jj];
    }
    __syncthreads();
    {
      const int nn = tid>>3, q = tid&7;
      float* dst = C + ((u64)t*G3 + n0 + half*32 + nn)*BSZ + q*16;
      const float* srow = &As[nn][q*16];
      float4 v0=*(const float4*)(srow+0), v1=*(const float4*)(srow+4);
      float4 v2=*(const float4*)(srow+8), v3=*(const float4*)(srow+12);
      *(float4*)(dst+0)=v0; *(float4*)(dst+4)=v1; *(float4*)(dst+8)=v2; *(float4*)(dst+12)=v3;
    }
    __syncthreads();
  }
}

// persistent masked GRU scan (round-14): f32 h states, 1 barrier/step
template<bool BWD, bool ACCUM>
__global__ __launch_bounds__(512)
void scan_kernel(u64 gx_f, u64 p0_f, u64 p1_f,
                 const float* __restrict__ whh, const float* __restrict__ bhh,
                 const int* __restrict__ lengths, u64 out_f)
{
  __shared__ u16 wl[HDIM*12];
  __shared__ float red[8*12*128];
  const int bid = blockIdx.x, tid = threadIdx.x;
  const int j0 = bid*4;
  #pragma unroll
  for (int r=0;r<12;++r){
    const int row = (r>>2)*HDIM + j0 + (r&3);
    for (int k=tid;k<HDIM;k+=512) wl[k*12+r] = f2b(whh[(u64)row*HDIM + k]);
  }
  __syncthreads();

  const int jl = tid>>7, bb = tid&127;
  const int jg = j0 + jl;
  for (int s=0; s<TLEN; ++s){
    const int t = BWD ? (TLEN-1-s) : s;
    const u64 rd = (s&1)? p0_f : p1_f;
    const u64 wr = (s&1)? p1_f : p0_f;
    if (s>0){
      float acc[12][2];
      ggemm12(wl, g_pool + rd, acc, tid);
      reduce12(acc, red, tid);
    }
    const float* gxb = g_pool + gx_f + (u64)t*G3*BSZ;
    {
      const int len = lengths[bb];
      const bool m = (t < len);
      float gh0=0.f, gh1=0.f, gh2=0.f;
      if (s>0){
        #pragma unroll
        for (int w2=0;w2<8;++w2){
          gh0 += red[(u64)(w2*12 + jl)*128 + bb];
          gh1 += red[(u64)(w2*12 + 4 + jl)*128 + bb];
          gh2 += red[(u64)(w2*12 + 8 + jl)*128 + bb];
        }
      }
      const float xr = gxb[(u64)jg*BSZ + bb];
      const float xz = gxb[(u64)(HDIM+jg)*BSZ + bb];
      const float xn = gxb[(u64)(2*HDIM+jg)*BSZ + bb];
      const float hp = (s>0)? g_pool[rd + (u64)jg*BSZ + bb] : 0.f;
      const float r = sigmf(xr + gh0 + bhh[jg]);
      const float z = sigmf(xz + gh1 + bhh[HDIM+jg]);
      const float n = tanhf(xn + r*(gh2 + bhh[2*HDIM+jg]));
      const float hv = (1.f-z)*n + z*hp;
      g_pool[wr + (u64)jg*BSZ + bb] = m ? hv : hp;
      const u64 oidx = out_f + ((u64)t*HDIM + jg)*BSZ + bb;
      if (ACCUM){ if (m) g_pool[oidx] += hv; }
      else g_pool[oidx] = m ? hv : 0.f;
    }
    grid_sync();
  }
}

// one-time converters: cw/ow -> bf16; decoder init states f32->bf16
__global__ __launch_bounds__(256)
void conv_w(const float* __restrict__ cw, const float* __restrict__ ow){
  u16* cwb = (u16*)(g_pool + F_CWB);
  u16* owb = (u16*)(g_pool + F_OWB);
  u16* hi0 = (u16*)(g_pool + F_SHI0);
  u16* hi1 = (u16*)(g_pool + F_SHI1);
  const u64 n1 = (u64)HDIM*2*HDIM;
  const u64 n2 = (u64)NTAG*HDIM;
  const u64 n3 = (u64)HDIM*BSZ;
  for (u64 i = (u64)blockIdx.x*256+threadIdx.x; i<n1; i += (u64)gridDim.x*256) cwb[i]=f2b(cw[i]);
  for (u64 i = (u64)blockIdx.x*256+threadIdx.x; i<n2; i += (u64)gridDim.x*256) owb[i]=f2b(ow[i]);
  for (u64 i = (u64)blockIdx.x*256+threadIdx.x; i<n3; i += (u64)gridDim.x*256){
    hi0[i]=f2b(g_pool[F_H0F + i]);
    hi1[i]=f2b(g_pool[F_H0B + i]);
  }
}
__global__ __launch_bounds__(256)
void enc_t(){
  const int t = blockIdx.x, kc = blockIdx.y;
  u16* etb = (u16*)(g_pool + F_ETB);
  for (int it=threadIdx.x; it<128*128; it+=256){
    const int kl = it>>7, b = it&127;
    const int k = kc*128 + kl;
    etb[(u64)b*(TLEN*HDIM) + (u64)t*HDIM + k] = f2b(g_pool[F_ENC + ((u64)t*HDIM+k)*BSZ + b]);
  }
}

// persistent decoder: 4 grid barriers per step; gather-not-scatter transposes
__global__ __launch_bounds__(512)
void decoder_kernel(const float* __restrict__ whh0, const float* __restrict__ bhh0,
                    const float* __restrict__ wih1, const float* __restrict__ bih1,
                    const float* __restrict__ whh1, const float* __restrict__ bhh1,
                    const float* __restrict__ cb, const float* __restrict__ ob,
                    const int* __restrict__ tag_ids, const int* __restrict__ lengths,
                    float* __restrict__ dout)
{
  __shared__ u16 wl0[HDIM*16];
  __shared__ u16 wl1[HDIM*16];
  __shared__ u16 wl2[HDIM*16];
  __shared__ float red[8*12*128];
  const int bid = blockIdx.x, tid = threadIdx.x;
  const int j0 = bid*4;
  const int w = tid>>6, l = tid&63;
  const int jl = tid>>7, bb = tid&127;
  const int jg = j0 + jl;

  #pragma unroll
  for (int r=0;r<12;++r){
    const int gr = (r>>2)*HDIM + j0 + (r&3);
    for (int k=tid;k<HDIM;k+=512){
      wl0[k*16+r] = f2b(whh0[(u64)gr*HDIM + k]);
      wl1[k*16+r] = f2b(wih1[(u64)gr*HDIM + k]);
      wl2[k*16+r] = f2b(whh1[(u64)gr*HDIM + k]);
    }
  }
  __syncthreads();

  const u16* etb = (const u16*)(g_pool + F_ETB);
  const u16* cwb = (const u16*)(g_pool + F_CWB);
  const u16* owb = (const u16*)(g_pool + F_OWB);
  u16* sctxR = (u16*)(g_pool + F_SCTXR);
  u16* scc   = (u16*)(g_pool + F_SCC);

  for (int t=0; t<TLEN; ++t){
    const u16* h0c = (const u16*)(g_pool + ((t==0)? F_SHI0 : ((t&1)? F_SH0A : F_SH0B)));
    u16*       h0n = (u16*)(g_pool + ((t&1)? F_SH0B : F_SH0A));
    const u16* h1c = (const u16*)(g_pool + ((t==0)? F_SHI1 : ((t&1)? F_SH1A : F_SH1B)));
    u16*       h1n = (u16*)(g_pool + ((t&1)? F_SH1B : F_SH1A));

    // ---- P1: layer-0 GRU ----
    {
      float acc[12][2];
      ggemm12u(wl0, h0c, acc, tid);
      reduce12(acc, red, tid);
      const float* gxb = g_pool + F_GX + (u64)t*G3*BSZ;
      float gh0=0.f, gh1=0.f, gh2=0.f;
      #pragma unroll
      for (int w2=0;w2<8;++w2){
        gh0 += red[(u64)(w2*12 + jl)*128 + bb];
        gh1 += red[(u64)(w2*12 + 4 + jl)*128 + bb];
        gh2 += red[(u64)(w2*12 + 8 + jl)*128 + bb];
      }
      const float xr = gxb[(u64)jg*BSZ+bb], xz = gxb[(u64)(HDIM+jg)*BSZ+bb], xn = gxb[(u64)(2*HDIM+jg)*BSZ+bb];
      const float hp = b2f(h0c[(u64)jg*BSZ + bb]);
      const float r = sigmf(xr + gh0 + bhh0[jg]);
      const float z = sigmf(xz + gh1 + bhh0[HDIM+jg]);
      const float n = tanhf(xn + r*(gh2 + bhh0[2*HDIM+jg]));
      h0n[(u64)jg*BSZ + bb] = f2b((1.f-z)*n + z*hp);
    }
    grid_sync();   // b1

    // ---- P2: layer-1 GRU ----
    {
      float acc[12][2];
      float aX[3], aH[3];
      ggemm12u(wl1, h0n, acc, tid);
      reduce12(acc, red, tid);
      #pragma unroll
      for (int g=0;g<3;++g){
        float s=0.f;
        #pragma unroll
        for (int w2=0;w2<8;++w2) s += red[(u64)(w2*12 + g*4 + jl)*128 + bb];
        aX[g] = s;
      }
      ggemm12u(wl2, h1c, acc, tid);
      reduce12(acc, red, tid);
      #pragma unroll
      for (int g=0;g<3;++g){
        float s=0.f;
        #pragma unroll
        for (int w2=0;w2<8;++w2) s += red[(u64)(w2*12 + g*4 + jl)*128 + bb];
        aH[g] = s;
      }
      const float hp = b2f(h1c[(u64)jg*BSZ + bb]);
      const float r = sigmf(aX[0] + bih1[jg] + aH[0] + bhh1[jg]);
      const float z = sigmf(aX[1] + bih1[HDIM+jg] + aH[1] + bhh1[HDIM+jg]);
      const float n = tanhf(aX[2] + bih1[2*HDIM+jg] + r*(aH[2] + bhh1[2*HDIM+jg]));
      h1n[(u64)jg*BSZ + bb] = f2b((1.f-z)*n + z*hp);
    }
    grid_sync();   // b2

    // ---- P34: per-b attention (blocks 0..127); scores+softmax+ctx fused ----
    {
      float* hLp = red;            // [64*17]
      float* sc  = red + 1100;     // [64]
      float* aw  = red + 1164;     // [64]
      const int b = bid;
      if (bid < 128){
        const int k = tid*2;
        const float v0 = b2f(h1n[(u64)k*BSZ + b]);
        const float v1 = b2f(h1n[(u64)(k+1)*BSZ + b]);
        const int c = k>>4, i = k&15;
        hLp[c*17+i] = v0; hLp[c*17+i+1] = v1;
      }
      __syncthreads();
      if (bid < 128){
        const u16* eb = etb + (u64)b*(TLEN*HDIM);
        for (int tp=w; tp<TLEN; tp+=8){
          const u16* er = eb + (u64)tp*HDIM + l*16;
          uint4 e0 = *(const uint4*)er;
          uint4 e1 = *(const uint4*)(er+8);
          const float* hp = &hLp[l*17];
          float s = b2f_lo(e0.x)*hp[0] + b2f_hi(e0.x)*hp[1]
                  + b2f_lo(e0.y)*hp[2] + b2f_hi(e0.y)*hp[3]
                  + b2f_lo(e0.z)*hp[4] + b2f_hi(e0.z)*hp[5]
                  + b2f_lo(e0.w)*hp[6] + b2f_hi(e0.w)*hp[7]
                  + b2f_lo(e1.x)*hp[8] + b2f_hi(e1.x)*hp[9]
                  + b2f_lo(e1.y)*hp[10] + b2f_hi(e1.y)*hp[11]
                  + b2f_lo(e1.z)*hp[12] + b2f_hi(e1.z)*hp[13]
                  + b2f_lo(e1.w)*hp[14] + b2f_hi(e1.w)*hp[15];
          #pragma unroll
          for (int o=32;o;o>>=1) s += __shfl_xor(s, o);
          if (l==0) sc[tp] = s;
        }
      }
      __syncthreads();
      if (bid < 128 && tid < 64){
        float v = (tid<TLEN)? sc[tid] : -1e30f;
        float mx = v;
        #pragma unroll
        for (int o=32;o;o>>=1) mx = fmaxf(mx, __shfl_xor(mx,o));
        float e = (tid<TLEN)? __expf(v-mx) : 0.f;
        float sm = e;
        #pragma unroll
        for (int o=32;o;o>>=1) sm += __shfl_xor(sm,o);
        if (tid < TLEN) aw[tid] = e/sm;
      }
      __syncthreads();
      if (bid < 128){
        const u16* eb = etb + (u64)b*(TLEN*HDIM);
        const int k2 = tid*2;
        float a0=0.f, a1=0.f;
        #pragma unroll 10
        for (int tp=0;tp<TLEN;++tp){
          unsigned e = *(const unsigned*)(eb + (u64)tp*HDIM + k2);
          a0 += aw[tp]*b2f_lo(e); a1 += aw[tp]*b2f_hi(e);
        }
        const unsigned pk = (unsigned)f2b(a0) | ((unsigned)f2b(a1)<<16);
        *(unsigned*)(sctxR + (u64)b*HDIM + k2) = pk;   // coalesced row-major
      }
    }
    grid_sync();   // b3

    // ---- P5: cc (8 waves x K=256; 4 rows each) -> scc[n][b] ----
    {
      const int l2 = (tid&63)*2;
      const int k0 = w*256;
      const u16* wp0 = cwb + (u64)(j0+0)*2048 + k0;
      const u16* wp1 = cwb + (u64)(j0+1)*2048 + k0;
      const u16* wp2 = cwb + (u64)(j0+2)*2048 + k0;
      const u16* wp3 = cwb + (u64)(j0+3)*2048 + k0;
      float a0[4]={0,0,0,0}, a1v[4]={0,0,0,0};
      if (k0 < 1024){
        const u16* asrc = h1n + (u64)k0*BSZ;
        for (int kb=0; kb<256; kb+=16){
          unsigned a[16];
          #pragma unroll
          for (int u=0;u<16;++u) a[u] = *(const unsigned*)(asrc + (u64)(kb+u)*BSZ + l2);
          #pragma unroll
          for (int u=0;u<16;++u){
            const float ax = b2f_lo(a[u]), ay = b2f_hi(a[u]);
            const float w0v=b2f(wp0[kb+u]), w1v=b2f(wp1[kb+u]), w2v=b2f(wp2[kb+u]), w3v=b2f(wp3[kb+u]);
            a0[0]+=w0v*ax; a1v[0]+=w0v*ay;
            a0[1]+=w1v*ax; a1v[1]+=w1v*ay;
            a0[2]+=w2v*ax; a1v[2]+=w2v*ay;
            a0[3]+=w3v*ax; a1v[3]+=w3v*ay;
          }
        }
      } else {
        const int kc = k0 - 1024;
        const u16* c0 = sctxR + (u64)l2*HDIM + kc;
        const u16* c1 = sctxR + (u64)(l2+1)*HDIM + kc;
        for (int kb=0; kb<256; kb+=16){
          uint4 x0 = *(const uint4*)(c0+kb), x1 = *(const uint4*)(c0+kb+8);
          uint4 y0 = *(const uint4*)(c1+kb), y1 = *(const uint4*)(c1+kb+8);
          float ax[16], ay[16];
          ax[0]=b2f_lo(x0.x); ax[1]=b2f_hi(x0.x); ax[2]=b2f_lo(x0.y); ax[3]=b2f_hi(x0.y);
          ax[4]=b2f_lo(x0.z); ax[5]=b2f_hi(x0.z); ax[6]=b2f_lo(x0.w); ax[7]=b2f_hi(x0.w);
          ax[8]=b2f_lo(x1.x); ax[9]=b2f_hi(x1.x); ax[10]=b2f_lo(x1.y); ax[11]=b2f_hi(x1.y);
          ax[12]=b2f_lo(x1.z); ax[13]=b2f_hi(x1.z); ax[14]=b2f_lo(x1.w); ax[15]=b2f_hi(x1.w);
          ay[0]=b2f_lo(y0.x); ay[1]=b2f_hi(y0.x); ay[2]=b2f_lo(y0.y); ay[3]=b2f_hi(y0.y);
          ay[4]=b2f_lo(y0.z); ay[5]=b2f_hi(y0.z); ay[6]=b2f_lo(y0.w); ay[7]=b2f_hi(y0.w);
          ay[8]=b2f_lo(y1.x); ay[9]=b2f_hi(y1.x); ay[10]=b2f_lo(y1.y); ay[11]=b2f_hi(y1.y);
          ay[12]=b2f_lo(y1.z); ay[13]=b2f_hi(y1.z); ay[14]=b2f_lo(y1.w); ay[15]=b2f_hi(y1.w);
          #pragma unroll
          for (int u=0;u<16;++u){
            const float w0v=b2f(wp0[kb+u]), w1v=b2f(wp1[kb+u]), w2v=b2f(wp2[kb+u]), w3v=b2f(wp3[kb+u]);
            a0[0]+=w0v*ax[u]; a1v[0]+=w0v*ay[u];
            a0[1]+=w1v*ax[u]; a1v[1]+=w1v*ay[u];
            a0[2]+=w2v*ax[u]; a1v[2]+=w2v*ay[u];
            a0[3]+=w3v*ax[u]; a1v[3]+=w3v*ay[u];
          }
        }
      }
      __syncthreads();
      #pragma unroll
      for (int r=0;r<4;++r){
        red[(u64)(w*4+r)*128 + l2]   = a0[r];
        red[(u64)(w*4+r)*128 + l2+1] = a1v[r];
      }
      __syncthreads();
      {
        const int n2 = j0 + jl;
        float s = cb[n2];
        #pragma unroll
        for (int w2=0;w2<8;++w2) s += red[(u64)(w2*4+jl)*128 + bb];
        scc[(u64)n2*BSZ + bb] = f2b(tanhf(s));   // coalesced
      }
    }
    grid_sync();   // b4

    // ---- P67: per-b logits + softmax + nll (blocks 0..127) ----
    {
      float* ccfp = red;           // [64*17]
      float* lgL  = red + 1100;    // [256]
      float* rp   = red + 1356;    // [256]
      if (bid < 128){
        const int k = tid*2;
        const float v0 = b2f(scc[(u64)k*BSZ + bid]);
        const float v1 = b2f(scc[(u64)(k+1)*BSZ + bid]);
        const int c = k>>4, i = k&15;
        ccfp[c*17+i] = v0; ccfp[c*17+i+1] = v1;
      }
      __syncthreads();
      if (bid < 128){
        for (int v=w; v<NTAG; v+=8){
          const u16* owr = owb + (u64)v*HDIM + l*16;
          uint4 o0 = *(const uint4*)owr;
          uint4 o1 = *(const uint4*)(owr+8);
          const float* cp = &ccfp[l*17];
          float s = b2f_lo(o0.x)*cp[0] + b2f_hi(o0.x)*cp[1]
                  + b2f_lo(o0.y)*cp[2] + b2f_hi(o0.y)*cp[3]
                  + b2f_lo(o0.z)*cp[4] + b2f_hi(o0.z)*cp[5]
                  + b2f_lo(o0.w)*cp[6] + b2f_hi(o0.w)*cp[7]
                  + b2f_lo(o1.x)*cp[8] + b2f_hi(o1.x)*cp[9]
                  + b2f_lo(o1.y)*cp[10] + b2f_hi(o1.y)*cp[11]
                  + b2f_lo(o1.z)*cp[12] + b2f_hi(o1.z)*cp[13]
                  + b2f_lo(o1.w)*cp[14] + b2f_hi(o1.w)*cp[15];
          #pragma unroll
          for (int o=32;o;o>>=1) s += __shfl_xor(s, o);
          if (l==0) lgL[v] = s + ob[v];
        }
      }
      __syncthreads();
      const bool act = (bid < 128) && (tid < 256);
      float lg = 0.f;
      if (act){ lg = lgL[tid]; rp[tid] = lg; }
      __syncthreads();
      for (int o=128;o;o>>=1){ if (bid<128 && tid<o) rp[tid]=fmaxf(rp[tid],rp[tid+o]); __syncthreads(); }
      const float mx = (bid<128)? rp[0] : 0.f;
      __syncthreads();
      if (act) rp[tid] = __expf(lg-mx);
      __syncthreads();
      for (int o=128;o;o>>=1){ if (bid<128 && tid<o) rp[tid]+=rp[tid+o]; __syncthreads(); }
      if (act){
        const float lse = mx + __logf(rp[0]);
        dout[((u64)bid*TLEN + t)*NTAG + tid] = lg;
        if (tid==0){
          const int tag = tag_ids[bid*TLEN + t];
          g_pool[F_NLL + (u64)t*BSZ + bid] = lse - lgL[tag];
        }
      }
    }
    // no trailing barrier: next-step writers are ordered by b1/b2/b3
  }
  grid_sync();
  // ---- loss ----
  if (bid == 0){
    float ssum = 0.f;
    for (int i=tid; i<TLEN*BSZ; i+=512){
      const int tt = i>>7, b = i&127;
      if (tt < lengths[b]) ssum += g_pool[F_NLL + i];
    }
    red[tid] = ssum; __syncthreads();
    for (int o=256;o;o>>=1){ if (tid<o) red[tid]+=red[tid+o]; __syncthreads(); }
    if (tid==0){
      int den=0;
      for (int b=0;b<BSZ;b++) den += lengths[b];
      dout[(u64)BSZ*TLEN*NTAG] = red[0]/(float)den;
    }
  }
}

extern "C" void kernel_launch(void* const* d_in, const int* in_sizes, int n_in,
                              void* d_out, int out_size, void* d_ws, size_t ws_size,
                              hipStream_t stream)
{
  const float* enc_embed = (const float*)d_in[0];
  const float* e0_wih = (const float*)d_in[1];
  const float* e0_whh = (const float*)d_in[2];
  const float* e0_bih = (const float*)d_in[3];
  const float* e0_bhh = (const float*)d_in[4];
  const float* e1_wih = (const float*)d_in[5];
  const float* e1_whh = (const float*)d_in[6];
  const float* e1_bih = (const float*)d_in[7];
  const float* e1_bhh = (const float*)d_in[8];
  const float* dec_embed = (const float*)d_in[9];
  const float* d_wih = (const float*)d_in[10];
  const float* d_whh = (const float*)d_in[11];
  const float* d_bih = (const float*)d_in[12];
  const float* d_bhh = (const float*)d_in[13];
  const float* concat_w = (const float*)d_in[14];
  const float* concat_b = (const float*)d_in[15];
  const float* out_w = (const float*)d_in[16];
  const float* out_b = (const float*)d_in[17];
  const int* input_ids = (const int*)d_in[18];
  const int* tag_ids  = (const int*)d_in[19];
  const int* lengths  = (const int*)d_in[20];
  float* dout = (float*)d_out;

  const dim3 gxg(TLEN, G3/64);

  gemm_gx<AM_ENC><<<gxg,256,0,stream>>>(enc_embed,0,0,input_ids,e0_wih,e0_bih,F_GX,HDIM);
  scan_kernel<false,false><<<NBLK,512,0,stream>>>(F_GX, F_T0, F_H0F, e0_whh, e0_bhh, lengths, F_OF0);
  gemm_gx<AM_ENC><<<gxg,256,0,stream>>>(enc_embed,0,0,input_ids,
                                        e0_wih+(u64)G3*HDIM, e0_bih+G3, F_GX, HDIM);
  scan_kernel<true,false><<<NBLK,512,0,stream>>>(F_GX, F_T0, F_H0B,
                                        e0_whh+(u64)G3*HDIM, e0_bhh+G3, lengths, F_OB0);
  gemm_gx<AM_CAT><<<gxg,256,0,stream>>>(nullptr, F_OF0, F_OB0, nullptr,
                                        e1_wih, e1_bih, F_GX, 2*HDIM);
  scan_kernel<false,false><<<NBLK,512,0,stream>>>(F_GX, F_T0, F_T1, e1_whh, e1_bhh, lengths, F_ENC);
  gemm_gx<AM_CAT><<<gxg,256,0,stream>>>(nullptr, F_OF0, F_OB0, nullptr,
                                        e1_wih+(u64)G3*2*HDIM, e1_bih+G3, F_GX, 2*HDIM);
  scan_kernel<true,true><<<NBLK,512,0,stream>>>(F_GX, F_T0, F_T1,
                                        e1_whh+(u64)G3*HDIM, e1_bhh+G3, lengths, F_ENC);
  gemm_gx<AM_DEC><<<gxg,256,0,stream>>>(dec_embed,0,0,tag_ids, d_wih, d_bih, F_GX, HDIM);
  conv_w<<<256,256,0,stream>>>(concat_w, out_w);
  enc_t<<<dim3(TLEN,8),256,0,stream>>>();
  decoder_kernel<<<NBLK,512,0,stream>>>(d_whh, d_bhh,
                                        d_wih+(u64)G3*HDIM, d_bih+G3,
                                        d_whh+(u64)G3*HDIM, d_bhh+G3,
                                        concat_b, out_b,
                                        tag_ids, lengths, dout);
}

// Round 17
// 17100.943 us; speedup vs baseline: 2.0207x; 1.7279x over previous
//
#include <hip/hip_runtime.h>
#include <math.h>

#define HDIM 1024
#define NTAG 256
#define BSZ 128
#define TLEN 50
#define G3 3072
#define NBLK 256
#define NGRP 8

typedef unsigned long long u64;
typedef unsigned short u16;

constexpr u64 GX_F  = (u64)TLEN*G3*BSZ;
constexpr u64 SEQ_F = (u64)TLEN*HDIM*BSZ;
constexpr u64 HST_F = (u64)HDIM*BSZ;
constexpr u64 F_GX  = 0;
constexpr u64 F_OF0 = F_GX + GX_F;
constexpr u64 F_OB0 = F_OF0 + SEQ_F;
constexpr u64 F_ENC = F_OB0 + SEQ_F;
constexpr u64 F_T0  = F_ENC + SEQ_F;
constexpr u64 F_T1  = F_T0 + HST_F;
constexpr u64 F_H0F = F_T1 + HST_F;
constexpr u64 F_H0B = F_H0F + HST_F;
constexpr u64 F_CTXF= F_H0B + HST_F;    // unused scratch (layout stability)
constexpr u64 F_LG  = F_CTXF + HST_F;
constexpr u64 F_QP  = F_LG + (u64)NTAG*BSZ;
constexpr u64 F_NLL = F_QP + (u64)2*TLEN*BSZ;
constexpr u64 F_H1T = F_NLL + (u64)TLEN*BSZ;        // u16 [128][1024]
constexpr u64 F_CWB = F_H1T + 65536;                // u16 1024x2048
constexpr u64 F_OWB = F_CWB + 1048576;              // u16 256x1024
constexpr u64 F_ETB = F_OWB + 131072;               // u16 [128][50][1024]
constexpr u64 SHU   = 65536;
constexpr u64 F_SH0A= F_ETB + 3276800;
constexpr u64 F_SH0B= F_SH0A + SHU;
constexpr u64 F_SH1A= F_SH0B + SHU;
constexpr u64 F_SH1B= F_SH1A + SHU;
constexpr u64 F_SCTX= F_SH1B + SHU;
constexpr u64 F_SCC = F_SCTX + SHU;
constexpr u64 F_SHI0= F_SCC + SHU;
constexpr u64 F_SHI1= F_SHI0 + SHU;
constexpr u64 POOL_F= F_SHI1 + SHU;

__device__ __align__(256) float g_pool[POOL_F];
__device__ unsigned g_grp[NGRP*32];
__device__ unsigned g_root;
__device__ unsigned g_gen;

__device__ __forceinline__ float sigmf(float x){ return 1.f/(1.f+__expf(-x)); }
__device__ __forceinline__ u16 f2b(float x){
  unsigned u = __float_as_uint(x);
  u += 0x7fffu + ((u>>16)&1u);
  return (u16)(u>>16);
}
__device__ __forceinline__ float b2f(u16 s){ return __uint_as_float(((unsigned)s)<<16); }
__device__ __forceinline__ float b2f_lo(unsigned p){ return __uint_as_float(p<<16); }
__device__ __forceinline__ float b2f_hi(unsigned p){ return __uint_as_float(p & 0xffff0000u); }

// Tree barrier with RELAXED spins (no per-poll L2 invalidate on gfx950):
// - arrival add: RELEASE (one wbl2 publishes this block's writes)
// - spin: RELAXED agent loads (bypass L2, no invalidate)
// - exit: ONE ACQUIRE load (one L2 invalidate so we see remote writes)
__device__ __forceinline__ void grid_sync(){
  __syncthreads();
  if (threadIdx.x == 0){
    const int g = blockIdx.x & (NGRP-1);
    unsigned gen = __hip_atomic_load(&g_gen, __ATOMIC_RELAXED, __HIP_MEMORY_SCOPE_AGENT);
    unsigned old = __hip_atomic_fetch_add(&g_grp[g*32], 1u, __ATOMIC_RELEASE, __HIP_MEMORY_SCOPE_AGENT);
    if (old == (NBLK/NGRP)-1){
      unsigned ro = __hip_atomic_fetch_add(&g_root, 1u, __ATOMIC_RELEASE, __HIP_MEMORY_SCOPE_AGENT);
      if (ro == NGRP-1){
        __hip_atomic_store(&g_root, 0u, __ATOMIC_RELAXED, __HIP_MEMORY_SCOPE_AGENT);
        #pragma unroll
        for (int i=0;i<NGRP;++i)
          __hip_atomic_store(&g_grp[i*32], 0u, __ATOMIC_RELAXED, __HIP_MEMORY_SCOPE_AGENT);
        __hip_atomic_fetch_add(&g_gen, 1u, __ATOMIC_RELEASE, __HIP_MEMORY_SCOPE_AGENT);
      } else {
        while (__hip_atomic_load(&g_gen, __ATOMIC_RELAXED, __HIP_MEMORY_SCOPE_AGENT) == gen)
          __builtin_amdgcn_s_sleep(4);
      }
    } else {
      while (__hip_atomic_load(&g_gen, __ATOMIC_RELAXED, __HIP_MEMORY_SCOPE_AGENT) == gen)
        __builtin_amdgcn_s_sleep(4);
    }
    (void)__hip_atomic_load(&g_gen, __ATOMIC_ACQUIRE, __HIP_MEMORY_SCOPE_AGENT);
  }
  __syncthreads();
}

// 12-row GEMM, 8 waves x KPW=128, bf16 W in LDS [k*12], bf16 A [k][b], 16-deep prefetch
__device__ __forceinline__ void ggemm12u(const u16* __restrict__ wl,
                                         const u16* __restrict__ aT,
                                         float (&acc)[12][2], int tid)
{
  const int w = tid>>6, l2 = (tid&63)*2;
  #pragma unroll
  for (int r=0;r<12;++r){ acc[r][0]=0.f; acc[r][1]=0.f; }
  const int k0 = w*128;
  const u16* ap = aT + (u64)k0*BSZ + l2;
  const u16* wp = wl + k0*12;
  for (int kb=0; kb<128; kb+=16){
    unsigned a[16];
    #pragma unroll
    for (int u=0;u<16;++u) a[u] = *(const unsigned*)(ap + (u64)(kb+u)*BSZ);
    #pragma unroll
    for (int u=0;u<16;++u){
      const u16* wr = wp + (kb+u)*12;
      const float ax = b2f_lo(a[u]), ay = b2f_hi(a[u]);
      #pragma unroll
      for (int r=0;r<12;++r){
        const float wv = b2f(wr[r]);
        acc[r][0] += wv*ax; acc[r][1] += wv*ay;
      }
    }
  }
}

__device__ __forceinline__ void reduce12(const float (&acc)[12][2], float* red, int tid){
  const int w = tid>>6, l2 = (tid&63)*2;
  __syncthreads();
  #pragma unroll
  for (int r=0;r<12;++r){
    red[(u64)(w*12+r)*128 + l2]   = acc[r][0];
    red[(u64)(w*12+r)*128 + l2+1] = acc[r][1];
  }
  __syncthreads();
}

#define AM_ENC 0
#define AM_DEC 1
#define AM_CAT 2

template<int AMODE>
__global__ __launch_bounds__(256)
void gemm_gx(const float* __restrict__ embed,
             u64 a1_f, u64 a2_f,
             const int* __restrict__ ids,
             const float* __restrict__ W,
             const float* __restrict__ bias,
             u64 c_f, int K)
{
  constexpr int TM=128, TN=64, TK=32;
  __shared__ float As[TK][TM+4];
  __shared__ float Ws[TK][TN+4];
  __shared__ int rowid[TM];
  const int t = blockIdx.x;
  const int n0 = blockIdx.y*TN;
  const int tid = threadIdx.x;

  if (AMODE != AM_CAT){
    for (int r=tid; r<TM; r+=256)
      rowid[r] = (AMODE==AM_ENC) ? ids[r*TLEN+t] : ((t==0)?1:ids[r*TLEN+t-1]);
    __syncthreads();
  }

  const int tm = tid>>4, tn = tid&15;
  float acc[8][4];
  #pragma unroll
  for (int i=0;i<8;i++){ acc[i][0]=0.f;acc[i][1]=0.f;acc[i][2]=0.f;acc[i][3]=0.f; }

  for (int k0=0;k0<K;k0+=TK){
    if (AMODE==AM_CAT){
      const int kk = tid>>3, q = tid&7;
      const int kg = k0 + kk;
      const float* src = g_pool + ((kg<HDIM)? (a1_f + ((u64)t*HDIM + kg)*BSZ)
                                            : (a2_f + ((u64)t*HDIM + (kg-HDIM))*BSZ)) + q*16;
      float* d = &As[kk][q*16];
      float4 v0=*(const float4*)(src+0), v1=*(const float4*)(src+4);
      float4 v2=*(const float4*)(src+8), v3=*(const float4*)(src+12);
      *(float4*)(d+0)=v0; *(float4*)(d+4)=v1; *(float4*)(d+8)=v2; *(float4*)(d+12)=v3;
    } else {
      #pragma unroll
      for (int l=tid; l<TM*TK; l+=256){
        int r=l>>5, k=l&31;
        As[k][r] = embed[(u64)rowid[r]*HDIM + k0 + k];
      }
    }
    #pragma unroll
    for (int l=tid; l<TN*TK; l+=256){
      int n=l>>5, k=l&31;
      Ws[k][n] = W[(u64)(n0+n)*K + k0 + k];
    }
    __syncthreads();
    #pragma unroll 8
    for (int kk=0;kk<TK;kk++){
      float4 a0 = *(const float4*)&As[kk][tm*8];
      float4 a1 = *(const float4*)&As[kk][tm*8+4];
      float4 w  = *(const float4*)&Ws[kk][tn*4];
      float av[8]={a0.x,a0.y,a0.z,a0.w,a1.x,a1.y,a1.z,a1.w};
      float wv[4]={w.x,w.y,w.z,w.w};
      #pragma unroll
      for (int i=0;i<8;i++){
        #pragma unroll
        for (int jj=0;jj<4;jj++) acc[i][jj] += av[i]*wv[jj];
      }
    }
    __syncthreads();
  }

  float bv[4];
  #pragma unroll
  for (int jj=0;jj<4;jj++) bv[jj] = bias[n0+tn*4+jj];
  float* C = g_pool + c_f;
  for (int half=0; half<2; ++half){
    if ((tn>>3)==half){
      #pragma unroll
      for (int i=0;i<8;i++)
        #pragma unroll
        for (int jj=0;jj<4;jj++)
          As[(tn&7)*4+jj][tm*8+i] = acc[i][jj]+bv[jj];
    }
    __syncthreads();
    {
      const int nn = tid>>3, q = tid&7;
      float* dst = C + ((u64)t*G3 + n0 + half*32 + nn)*BSZ + q*16;
      const float* srow = &As[nn][q*16];
      float4 v0=*(const float4*)(srow+0), v1=*(const float4*)(srow+4);
      float4 v2=*(const float4*)(srow+8), v3=*(const float4*)(srow+12);
      *(float4*)(dst+0)=v0; *(float4*)(dst+4)=v1; *(float4*)(dst+8)=v2; *(float4*)(dst+12)=v3;
    }
    __syncthreads();
  }
}

// f32-A 12-row GEMM for scans
__device__ __forceinline__ void ggemm12(const u16* __restrict__ wl,
                                        const float* __restrict__ aT,
                                        float (&acc)[12][2], int tid)
{
  const int w = tid>>6, l2 = (tid&63)*2;
  #pragma unroll
  for (int r=0;r<12;++r){ acc[r][0]=0.f; acc[r][1]=0.f; }
  const int k0 = w*128;
  const float* ap = aT + (u64)k0*BSZ + l2;
  const u16* wp = wl + k0*12;
  for (int kb=0; kb<128; kb+=16){
    float2 a[16];
    #pragma unroll
    for (int u=0;u<16;++u) a[u] = *(const float2*)(ap + (u64)(kb+u)*BSZ);
    #pragma unroll
    for (int u=0;u<16;++u){
      const u16* wr = wp + (kb+u)*12;
      #pragma unroll
      for (int r=0;r<12;++r){
        const float wv = b2f(wr[r]);
        acc[r][0] += wv*a[u].x; acc[r][1] += wv*a[u].y;
      }
    }
  }
}

template<bool BWD, bool ACCUM>
__global__ __launch_bounds__(512)
void scan_kernel(u64 gx_f, u64 p0_f, u64 p1_f,
                 const float* __restrict__ whh, const float* __restrict__ bhh,
                 const int* __restrict__ lengths, u64 out_f)
{
  __shared__ u16 wl[HDIM*12];
  __shared__ float red[8*12*128];
  const int bid = blockIdx.x, tid = threadIdx.x;
  const int j0 = bid*4;
  #pragma unroll
  for (int r=0;r<12;++r){
    const int row = (r>>2)*HDIM + j0 + (r&3);
    for (int k=tid;k<HDIM;k+=512) wl[k*12+r] = f2b(whh[(u64)row*HDIM + k]);
  }
  __syncthreads();

  const int jl = tid>>7, bb = tid&127;
  const int jg = j0 + jl;
  for (int s=0; s<TLEN; ++s){
    const int t = BWD ? (TLEN-1-s) : s;
    const u64 rd = (s&1)? p0_f : p1_f;
    const u64 wr = (s&1)? p1_f : p0_f;
    if (s>0){
      float acc[12][2];
      ggemm12(wl, g_pool + rd, acc, tid);
      reduce12(acc, red, tid);
    }
    const float* gxb = g_pool + gx_f + (u64)t*G3*BSZ;
    {
      const int len = lengths[bb];
      const bool m = (t < len);
      float gh0=0.f, gh1=0.f, gh2=0.f;
      if (s>0){
        #pragma unroll
        for (int w2=0;w2<8;++w2){
          gh0 += red[(u64)(w2*12 + jl)*128 + bb];
          gh1 += red[(u64)(w2*12 + 4 + jl)*128 + bb];
          gh2 += red[(u64)(w2*12 + 8 + jl)*128 + bb];
        }
      }
      const float xr = gxb[(u64)jg*BSZ + bb];
      const float xz = gxb[(u64)(HDIM+jg)*BSZ + bb];
      const float xn = gxb[(u64)(2*HDIM+jg)*BSZ + bb];
      const float hp = (s>0)? g_pool[rd + (u64)jg*BSZ + bb] : 0.f;
      const float r = sigmf(xr + gh0 + bhh[jg]);
      const float z = sigmf(xz + gh1 + bhh[HDIM+jg]);
      const float n = tanhf(xn + r*(gh2 + bhh[2*HDIM+jg]));
      const float hv = (1.f-z)*n + z*hp;
      g_pool[wr + (u64)jg*BSZ + bb] = m ? hv : hp;
      const u64 oidx = out_f + ((u64)t*HDIM + jg)*BSZ + bb;
      if (ACCUM){ if (m) g_pool[oidx] += hv; }
      else g_pool[oidx] = m ? hv : 0.f;
    }
    grid_sync();
  }
}

// one-time converters: cw/ow -> bf16, decoder initial states -> bf16
__global__ __launch_bounds__(256)
void conv_w(const float* __restrict__ cw, const float* __restrict__ ow){
  u16* cwb = (u16*)(g_pool + F_CWB);
  u16* owb = (u16*)(g_pool + F_OWB);
  u16* hi0 = (u16*)(g_pool + F_SHI0);
  u16* hi1 = (u16*)(g_pool + F_SHI1);
  const u64 n1 = (u64)HDIM*2*HDIM;
  const u64 n2 = (u64)NTAG*HDIM;
  const u64 n3 = (u64)HDIM*BSZ;
  for (u64 i = (u64)blockIdx.x*256+threadIdx.x; i<n1; i += (u64)gridDim.x*256) cwb[i]=f2b(cw[i]);
  for (u64 i = (u64)blockIdx.x*256+threadIdx.x; i<n2; i += (u64)gridDim.x*256) owb[i]=f2b(ow[i]);
  for (u64 i = (u64)blockIdx.x*256+threadIdx.x; i<n3; i += (u64)gridDim.x*256){
    hi0[i]=f2b(g_pool[F_H0F + i]);
    hi1[i]=f2b(g_pool[F_H0B + i]);
  }
}
__global__ __launch_bounds__(256)
void enc_t(){
  const int t = blockIdx.x, kc = blockIdx.y;
  u16* etb = (u16*)(g_pool + F_ETB);
  for (int it=threadIdx.x; it<128*128; it+=256){
    const int kl = it>>7, b = it&127;
    const int k = kc*128 + kl;
    etb[(u64)b*(TLEN*HDIM) + (u64)t*HDIM + k] = f2b(g_pool[F_ENC + ((u64)t*HDIM+k)*BSZ + b]);
  }
}

// persistent decoder: 256 blocks x 512 threads; all states bf16 [k][b]
__global__ __launch_bounds__(512)
void decoder_kernel(const float* __restrict__ whh0, const float* __restrict__ bhh0,
                    const float* __restrict__ wih1, const float* __restrict__ bih1,
                    const float* __restrict__ whh1, const float* __restrict__ bhh1,
                    const float* __restrict__ cb, const float* __restrict__ ob,
                    const int* __restrict__ tag_ids, const int* __restrict__ lengths,
                    float* __restrict__ dout)
{
  __shared__ u16 wl0[HDIM*12];
  __shared__ u16 wl1[HDIM*12];
  __shared__ u16 wl2[HDIM*12];
  __shared__ float red[8*12*128];
  __shared__ float aL[64];
  const int bid = blockIdx.x, tid = threadIdx.x;
  const int j0 = bid*4;
  const int ab = bid>>1, kh2 = bid&1;
  const int w = tid>>6, l2 = (tid&63)*2, l = tid&63;
  const int jl = tid>>7, bb = tid&127;
  const int jg = j0 + jl;

  #pragma unroll
  for (int r=0;r<12;++r){
    const int gr = (r>>2)*HDIM + j0 + (r&3);
    for (int k=tid;k<HDIM;k+=512){
      wl0[k*12+r] = f2b(whh0[(u64)gr*HDIM + k]);
      wl1[k*12+r] = f2b(wih1[(u64)gr*HDIM + k]);
      wl2[k*12+r] = f2b(whh1[(u64)gr*HDIM + k]);
    }
  }
  __syncthreads();

  u16* h1t = (u16*)(g_pool + F_H1T);
  const u16* etb = (const u16*)(g_pool + F_ETB);
  const u16* cwb = (const u16*)(g_pool + F_CWB);
  const u16* owb = (const u16*)(g_pool + F_OWB);
  u16* sctx = (u16*)(g_pool + F_SCTX);
  u16* scc  = (u16*)(g_pool + F_SCC);

  for (int t=0; t<TLEN; ++t){
    const u16* h0c = (const u16*)(g_pool + ((t==0)? F_SHI0 : ((t&1)? F_SH0A : F_SH0B)));
    u16*       h0n = (u16*)(g_pool + ((t&1)? F_SH0B : F_SH0A));
    const u16* h1c = (const u16*)(g_pool + ((t==0)? F_SHI1 : ((t&1)? F_SH1A : F_SH1B)));
    u16*       h1n = (u16*)(g_pool + ((t&1)? F_SH1B : F_SH1A));

    // ---- P1: layer-0 GRU ----
    {
      float acc[12][2];
      ggemm12u(wl0, h0c, acc, tid);
      reduce12(acc, red, tid);
      const float* gxb = g_pool + F_GX + (u64)t*G3*BSZ;
      float gh0=0.f, gh1=0.f, gh2=0.f;
      #pragma unroll
      for (int w2=0;w2<8;++w2){
        gh0 += red[(u64)(w2*12 + jl)*128 + bb];
        gh1 += red[(u64)(w2*12 + 4 + jl)*128 + bb];
        gh2 += red[(u64)(w2*12 + 8 + jl)*128 + bb];
      }
      const float xr = gxb[(u64)jg*BSZ+bb], xz = gxb[(u64)(HDIM+jg)*BSZ+bb], xn = gxb[(u64)(2*HDIM+jg)*BSZ+bb];
      const float hp = b2f(h0c[(u64)jg*BSZ + bb]);
      const float r = sigmf(xr + gh0 + bhh0[jg]);
      const float z = sigmf(xz + gh1 + bhh0[HDIM+jg]);
      const float n = tanhf(xn + r*(gh2 + bhh0[2*HDIM+jg]));
      h0n[(u64)jg*BSZ + bb] = f2b((1.f-z)*n + z*hp);
    }
    grid_sync();   // b1

    // ---- P2: layer-1 GRU (two GEMMs) ----
    {
      float acc[12][2];
      float aX[3], aH[3];
      ggemm12u(wl1, h0n, acc, tid);
      reduce12(acc, red, tid);
      #pragma unroll
      for (int g=0;g<3;++g){
        float s=0.f;
        #pragma unroll
        for (int w2=0;w2<8;++w2) s += red[(u64)(w2*12 + g*4 + jl)*128 + bb];
        aX[g] = s;
      }
      ggemm12u(wl2, h1c, acc, tid);
      reduce12(acc, red, tid);
      #pragma unroll
      for (int g=0;g<3;++g){
        float s=0.f;
        #pragma unroll
        for (int w2=0;w2<8;++w2) s += red[(u64)(w2*12 + g*4 + jl)*128 + bb];
        aH[g] = s;
      }
      const float hp = b2f(h1c[(u64)jg*BSZ + bb]);
      const float r = sigmf(aX[0] + bih1[jg] + aH[0] + bhh1[jg]);
      const float z = sigmf(aX[1] + bih1[HDIM+jg] + aH[1] + bhh1[HDIM+jg]);
      const float n = tanhf(aX[2] + bih1[2*HDIM+jg] + r*(aH[2] + bhh1[2*HDIM+jg]));
      const float hv = (1.f-z)*n + z*hp;
      const u16 hb = f2b(hv);
      h1n[(u64)jg*BSZ + bb] = hb;
      h1t[(u64)bb*HDIM + jg] = hb;
    }
    grid_sync();   // b2

    // ---- P3: score partials (block = (b=ab, k-half=kh2); 8 waves over tp) ----
    {
      const u16* h1r = h1t + (u64)ab*HDIM + kh2*512 + l*8;
      float hv[8];
      #pragma unroll
      for (int u=0;u<8;++u) hv[u] = b2f(h1r[u]);
      for (int tp=w; tp<TLEN; tp+=8){
        const u16* er = etb + (u64)ab*(TLEN*HDIM) + (u64)tp*HDIM + kh2*512 + l*8;
        float s=0.f;
        #pragma unroll
        for (int u=0;u<8;++u) s += hv[u]*b2f(er[u]);
        #pragma unroll
        for (int o=32;o;o>>=1) s += __shfl_xor(s, o);
        if (l==0) g_pool[F_QP + (u64)kh2*TLEN*BSZ + (u64)tp*BSZ + ab] = s;
      }
    }
    grid_sync();   // b3

    // ---- P4: softmax (redundant per pair) + ctx half from etb ----
    {
      if (tid < 64){
        float v = -1e30f;
        if (tid < TLEN)
          v = g_pool[F_QP + (u64)tid*BSZ + ab] + g_pool[F_QP + (u64)(TLEN+tid)*BSZ + ab];
        float mx = v;
        #pragma unroll
        for (int o=32;o;o>>=1) mx = fmaxf(mx, __shfl_xor(mx,o));
        float e = (tid<TLEN)? __expf(v-mx) : 0.f;
        float sm = e;
        #pragma unroll
        for (int o=32;o;o>>=1) sm += __shfl_xor(sm,o);
        if (tid < TLEN) aL[tid] = e/sm;
      }
      __syncthreads();
      {
        const int kk = tid;
        const u16* eb = etb + (u64)ab*(TLEN*HDIM) + kh2*512 + kk;
        float acc = 0.f;
        #pragma unroll 10
        for (int tp=0;tp<TLEN;++tp) acc += aL[tp]*b2f(eb[(u64)tp*HDIM]);
        sctx[(u64)(kh2*512+kk)*BSZ + ab] = f2b(acc);
      }
    }
    grid_sync();   // b4

    // ---- P5: cc (8 waves x K=256 slices; 4 rows each; cross-wave reduce) ----
    {
      const int k0 = w*256;
      const u16* asrc = (k0<1024)? ((const u16*)(g_pool + ((t&1)? F_SH1B : F_SH1A)) + (u64)k0*BSZ)
                                 : (sctx + (u64)(k0-1024)*BSZ);
      const u16* wp0 = cwb + (u64)(j0+0)*2048 + k0;
      const u16* wp1 = cwb + (u64)(j0+1)*2048 + k0;
      const u16* wp2 = cwb + (u64)(j0+2)*2048 + k0;
      const u16* wp3 = cwb + (u64)(j0+3)*2048 + k0;
      float a0[4]={0,0,0,0}, a1v[4]={0,0,0,0};
      for (int kb=0; kb<256; kb+=16){
        unsigned a[16];
        #pragma unroll
        for (int u=0;u<16;++u) a[u] = *(const unsigned*)(asrc + (u64)(kb+u)*BSZ + l2);
        #pragma unroll
        for (int u=0;u<16;++u){
          const float ax = b2f_lo(a[u]), ay = b2f_hi(a[u]);
          const float w0v=b2f(wp0[kb+u]), w1v=b2f(wp1[kb+u]), w2v=b2f(wp2[kb+u]), w3v=b2f(wp3[kb+u]);
          a0[0]+=w0v*ax; a1v[0]+=w0v*ay;
          a0[1]+=w1v*ax; a1v[1]+=w1v*ay;
          a0[2]+=w2v*ax; a1v[2]+=w2v*ay;
          a0[3]+=w3v*ax; a1v[3]+=w3v*ay;
        }
      }
      __syncthreads();
      #pragma unroll
      for (int r=0;r<4;++r){
        red[(u64)(w*4+r)*128 + l2]   = a0[r];
        red[(u64)(w*4+r)*128 + l2+1] = a1v[r];
      }
      __syncthreads();
      {
        const int n2 = j0 + jl;
        float s = cb[n2];
        #pragma unroll
        for (int w2=0;w2<8;++w2) s += red[(u64)(w2*4+jl)*128 + bb];
        scc[(u64)n2*BSZ + bb] = f2b(tanhf(s));
      }
    }
    grid_sync();   // b5

    // ---- P6: logits row v=bid (8-way k-split, bf16 ow + bf16 cc) ----
    {
      const u16* owv = owb + (u64)bid*HDIM + w*128;
      const u16* ccp = scc + (u64)w*128*BSZ;
      float a0=0.f, a1v=0.f;
      for (int kb=0; kb<128; kb+=16){
        unsigned a[16];
        #pragma unroll
        for (int u=0;u<16;++u) a[u] = *(const unsigned*)(ccp + (u64)(kb+u)*BSZ + l2);
        #pragma unroll
        for (int u=0;u<16;++u){
          const float wv = b2f(owv[kb+u]);
          a0 += wv*b2f_lo(a[u]); a1v += wv*b2f_hi(a[u]);
        }
      }
      __syncthreads();
      red[(u64)w*128 + l2]   = a0;
      red[(u64)w*128 + l2+1] = a1v;
      __syncthreads();
      if (tid < 128){
        float lg = ob[bid];
        #pragma unroll
        for (int w2=0;w2<8;++w2) lg += red[(u64)w2*128 + tid];
        g_pool[F_LG + (u64)bid*BSZ + tid] = lg;
      }
    }
    grid_sync();   // b6

    // ---- P7: per-b softmax + nll ----
    {
      float* lgs = red;
      float* rp  = red + 256;
      const bool act = (bid < BSZ) && (tid < 256);
      float lg = 0.f;
      if (act){
        lg = g_pool[F_LG + (u64)tid*BSZ + bid];
        lgs[tid] = lg; rp[tid] = lg;
      }
      __syncthreads();
      for (int o=128;o;o>>=1){ if (bid<BSZ && tid<o) rp[tid]=fmaxf(rp[tid],rp[tid+o]); __syncthreads(); }
      const float mx = (bid<BSZ)? rp[0] : 0.f;
      __syncthreads();
      if (act) rp[tid] = __expf(lg-mx);
      __syncthreads();
      for (int o=128;o;o>>=1){ if (bid<BSZ && tid<o) rp[tid]+=rp[tid+o]; __syncthreads(); }
      if (act){
        const float lse = mx + __logf(rp[0]);
        dout[((u64)bid*TLEN + t)*NTAG + tid] = lg;
        if (tid==0){
          const int tag = tag_ids[bid*TLEN + t];
          g_pool[F_NLL + (u64)t*BSZ + bid] = lse - lgs[tag];
        }
      }
    }
  }
  grid_sync();
  // ---- loss ----
  if (bid == 0){
    float ssum = 0.f;
    for (int i=tid; i<TLEN*BSZ; i+=512){
      const int tt = i>>7, b = i&127;
      if (tt < lengths[b]) ssum += g_pool[F_NLL + i];
    }
    red[tid] = ssum; __syncthreads();
    for (int o=256;o;o>>=1){ if (tid<o) red[tid]+=red[tid+o]; __syncthreads(); }
    if (tid==0){
      int den=0;
      for (int b=0;b<BSZ;b++) den += lengths[b];
      dout[(u64)BSZ*TLEN*NTAG] = red[0]/(float)den;
    }
  }
}

extern "C" void kernel_launch(void* const* d_in, const int* in_sizes, int n_in,
                              void* d_out, int out_size, void* d_ws, size_t ws_size,
                              hipStream_t stream)
{
  const float* enc_embed = (const float*)d_in[0];
  const float* e0_wih = (const float*)d_in[1];
  const float* e0_whh = (const float*)d_in[2];
  const float* e0_bih = (const float*)d_in[3];
  const float* e0_bhh = (const float*)d_in[4];
  const float* e1_wih = (const float*)d_in[5];
  const float* e1_whh = (const float*)d_in[6];
  const float* e1_bih = (const float*)d_in[7];
  const float* e1_bhh = (const float*)d_in[8];
  const float* dec_embed = (const float*)d_in[9];
  const float* d_wih = (const float*)d_in[10];
  const float* d_whh = (const float*)d_in[11];
  const float* d_bih = (const float*)d_in[12];
  const float* d_bhh = (const float*)d_in[13];
  const float* concat_w = (const float*)d_in[14];
  const float* concat_b = (const float*)d_in[15];
  const float* out_w = (const float*)d_in[16];
  const float* out_b = (const float*)d_in[17];
  const int* input_ids = (const int*)d_in[18];
  const int* tag_ids  = (const int*)d_in[19];
  const int* lengths  = (const int*)d_in[20];
  float* dout = (float*)d_out;

  const dim3 gxg(TLEN, G3/64);

  gemm_gx<AM_ENC><<<gxg,256,0,stream>>>(enc_embed,0,0,input_ids,e0_wih,e0_bih,F_GX,HDIM);
  scan_kernel<false,false><<<NBLK,512,0,stream>>>(F_GX, F_T0, F_H0F, e0_whh, e0_bhh, lengths, F_OF0);
  gemm_gx<AM_ENC><<<gxg,256,0,stream>>>(enc_embed,0,0,input_ids,
                                        e0_wih+(u64)G3*HDIM, e0_bih+G3, F_GX, HDIM);
  scan_kernel<true,false><<<NBLK,512,0,stream>>>(F_GX, F_T0, F_H0B,
                                        e0_whh+(u64)G3*HDIM, e0_bhh+G3, lengths, F_OB0);
  gemm_gx<AM_CAT><<<gxg,256,0,stream>>>(nullptr, F_OF0, F_OB0, nullptr,
                                        e1_wih, e1_bih, F_GX, 2*HDIM);
  scan_kernel<false,false><<<NBLK,512,0,stream>>>(F_GX, F_T0, F_T1, e1_whh, e1_bhh, lengths, F_ENC);
  gemm_gx<AM_CAT><<<gxg,256,0,stream>>>(nullptr, F_OF0, F_OB0, nullptr,
                                        e1_wih+(u64)G3*2*HDIM, e1_bih+G3, F_GX, 2*HDIM);
  scan_kernel<true,true><<<NBLK,512,0,stream>>>(F_GX, F_T0, F_T1,
                                        e1_whh+(u64)G3*HDIM, e1_bhh+G3, lengths, F_ENC);
  gemm_gx<AM_DEC><<<gxg,256,0,stream>>>(dec_embed,0,0,tag_ids, d_wih, d_bih, F_GX, HDIM);
  conv_w<<<256,256,0,stream>>>(concat_w, out_w);
  enc_t<<<dim3(TLEN,8),256,0,stream>>>();
  decoder_kernel<<<NBLK,512,0,stream>>>(d_whh, d_bhh,
                                        d_wih+(u64)G3*HDIM, d_bih+G3,
                                        d_whh+(u64)G3*HDIM, d_bhh+G3,
                                        concat_b, out_b,
                                        tag_ids, lengths, dout);
}

// Round 18
// 17090.936 us; speedup vs baseline: 2.0219x; 1.0006x over previous
//
#include <hip/hip_runtime.h>
#include <math.h>

#define HDIM 1024
#define NTAG 256
#define BSZ 128
#define TLEN 50
#define G3 3072
#define NBLK 256
#define NGRP 8

typedef unsigned long long u64;
typedef unsigned short u16;

constexpr u64 GX_F  = (u64)TLEN*G3*BSZ;
constexpr u64 SEQ_F = (u64)TLEN*HDIM*BSZ;
constexpr u64 HST_F = (u64)HDIM*BSZ;
constexpr u64 F_GX  = 0;
constexpr u64 F_GXB = F_GX + GX_F;
constexpr u64 F_OF0 = F_GXB + GX_F;
constexpr u64 F_OB0 = F_OF0 + SEQ_F;
constexpr u64 F_ENC = F_OB0 + SEQ_F;
constexpr u64 F_ENC2= F_ENC + SEQ_F;
constexpr u64 F_T0  = F_ENC2 + SEQ_F;
constexpr u64 F_T1  = F_T0 + HST_F;
constexpr u64 F_H0F = F_T1 + HST_F;
constexpr u64 F_H0B = F_H0F + HST_F;
constexpr u64 F_X0  = F_H0B + HST_F;
constexpr u64 F_X1  = F_X0 + HST_F;
constexpr u64 F_LG  = F_X1 + HST_F;
constexpr u64 F_QP  = F_LG + (u64)NTAG*BSZ;
constexpr u64 F_NLL = F_QP + (u64)2*TLEN*BSZ;
constexpr u64 F_H1T = F_NLL + (u64)TLEN*BSZ;        // u16 [128][1024]
constexpr u64 F_CWB = F_H1T + 65536;                // u16 1024x2048
constexpr u64 F_OWB = F_CWB + 1048576;              // u16 256x1024
constexpr u64 F_ETB = F_OWB + 131072;               // u16 [128][50][1024]
constexpr u64 SHU   = 65536;
constexpr u64 F_SH0A= F_ETB + 3276800;
constexpr u64 F_SH0B= F_SH0A + SHU;
constexpr u64 F_SH1A= F_SH0B + SHU;
constexpr u64 F_SH1B= F_SH1A + SHU;
constexpr u64 F_SCTX= F_SH1B + SHU;
constexpr u64 F_SCC = F_SCTX + SHU;
constexpr u64 F_SHI0= F_SCC + SHU;
constexpr u64 F_SHI1= F_SHI0 + SHU;
constexpr u64 POOL_F= F_SHI1 + SHU;

__device__ __align__(256) float g_pool[POOL_F];
__device__ unsigned g_grp[NGRP*32];
__device__ unsigned g_root;
__device__ unsigned g_gen;
__device__ unsigned g2_grp[2*NGRP*32];
__device__ unsigned g2_root[2*32];
__device__ unsigned g2_gen[2*32];

__device__ __forceinline__ float sigmf(float x){ return 1.f/(1.f+__expf(-x)); }
__device__ __forceinline__ u16 f2b(float x){
  unsigned u = __float_as_uint(x);
  u += 0x7fffu + ((u>>16)&1u);
  return (u16)(u>>16);
}
__device__ __forceinline__ float b2f(u16 s){ return __uint_as_float(((unsigned)s)<<16); }
__device__ __forceinline__ float b2f_lo(unsigned p){ return __uint_as_float(p<<16); }
__device__ __forceinline__ float b2f_hi(unsigned p){ return __uint_as_float(p & 0xffff0000u); }

// relaxed-spin tree barrier (single grid of 256)
__device__ __forceinline__ void grid_sync(){
  __syncthreads();
  if (threadIdx.x == 0){
    const int g = blockIdx.x & (NGRP-1);
    unsigned gen = __hip_atomic_load(&g_gen, __ATOMIC_RELAXED, __HIP_MEMORY_SCOPE_AGENT);
    unsigned old = __hip_atomic_fetch_add(&g_grp[g*32], 1u, __ATOMIC_RELEASE, __HIP_MEMORY_SCOPE_AGENT);
    if (old == (NBLK/NGRP)-1){
      unsigned ro = __hip_atomic_fetch_add(&g_root, 1u, __ATOMIC_RELEASE, __HIP_MEMORY_SCOPE_AGENT);
      if (ro == NGRP-1){
        __hip_atomic_store(&g_root, 0u, __ATOMIC_RELAXED, __HIP_MEMORY_SCOPE_AGENT);
        #pragma unroll
        for (int i=0;i<NGRP;++i)
          __hip_atomic_store(&g_grp[i*32], 0u, __ATOMIC_RELAXED, __HIP_MEMORY_SCOPE_AGENT);
        __hip_atomic_fetch_add(&g_gen, 1u, __ATOMIC_RELEASE, __HIP_MEMORY_SCOPE_AGENT);
      } else {
        while (__hip_atomic_load(&g_gen, __ATOMIC_RELAXED, __HIP_MEMORY_SCOPE_AGENT) == gen)
          __builtin_amdgcn_s_sleep(4);
      }
    } else {
      while (__hip_atomic_load(&g_gen, __ATOMIC_RELAXED, __HIP_MEMORY_SCOPE_AGENT) == gen)
        __builtin_amdgcn_s_sleep(4);
    }
    (void)__hip_atomic_load(&g_gen, __ATOMIC_ACQUIRE, __HIP_MEMORY_SCOPE_AGENT);
  }
  __syncthreads();
}

// per-half barrier for the paired scan kernel (two independent 256-block grids)
__device__ __forceinline__ void grid_sync_h(int half){
  __syncthreads();
  if (threadIdx.x == 0){
    const int g = (blockIdx.x & 255) & (NGRP-1);
    unsigned* grp  = &g2_grp[(half*NGRP + g)*32];
    unsigned* root = &g2_root[half*32];
    unsigned* genp = &g2_gen[half*32];
    unsigned gen = __hip_atomic_load(genp, __ATOMIC_RELAXED, __HIP_MEMORY_SCOPE_AGENT);
    unsigned old = __hip_atomic_fetch_add(grp, 1u, __ATOMIC_RELEASE, __HIP_MEMORY_SCOPE_AGENT);
    if (old == (NBLK/NGRP)-1){
      unsigned ro = __hip_atomic_fetch_add(root, 1u, __ATOMIC_RELEASE, __HIP_MEMORY_SCOPE_AGENT);
      if (ro == NGRP-1){
        __hip_atomic_store(root, 0u, __ATOMIC_RELAXED, __HIP_MEMORY_SCOPE_AGENT);
        #pragma unroll
        for (int i=0;i<NGRP;++i)
          __hip_atomic_store(&g2_grp[(half*NGRP + i)*32], 0u, __ATOMIC_RELAXED, __HIP_MEMORY_SCOPE_AGENT);
        __hip_atomic_fetch_add(genp, 1u, __ATOMIC_RELEASE, __HIP_MEMORY_SCOPE_AGENT);
      } else {
        while (__hip_atomic_load(genp, __ATOMIC_RELAXED, __HIP_MEMORY_SCOPE_AGENT) == gen)
          __builtin_amdgcn_s_sleep(4);
      }
    } else {
      while (__hip_atomic_load(genp, __ATOMIC_RELAXED, __HIP_MEMORY_SCOPE_AGENT) == gen)
        __builtin_amdgcn_s_sleep(4);
    }
    (void)__hip_atomic_load(genp, __ATOMIC_ACQUIRE, __HIP_MEMORY_SCOPE_AGENT);
  }
  __syncthreads();
}

// 12-row GEMM, 8 waves x KPW=128, bf16 W in LDS [k*12], bf16 A [k][b], 16-deep prefetch
__device__ __forceinline__ void ggemm12u(const u16* __restrict__ wl,
                                         const u16* __restrict__ aT,
                                         float (&acc)[12][2], int tid)
{
  const int w = tid>>6, l2 = (tid&63)*2;
  #pragma unroll
  for (int r=0;r<12;++r){ acc[r][0]=0.f; acc[r][1]=0.f; }
  const int k0 = w*128;
  const u16* ap = aT + (u64)k0*BSZ + l2;
  const u16* wp = wl + k0*12;
  for (int kb=0; kb<128; kb+=16){
    unsigned a[16];
    #pragma unroll
    for (int u=0;u<16;++u) a[u] = *(const unsigned*)(ap + (u64)(kb+u)*BSZ);
    #pragma unroll
    for (int u=0;u<16;++u){
      const u16* wr = wp + (kb+u)*12;
      const float ax = b2f_lo(a[u]), ay = b2f_hi(a[u]);
      #pragma unroll
      for (int r=0;r<12;++r){
        const float wv = b2f(wr[r]);
        acc[r][0] += wv*ax; acc[r][1] += wv*ay;
      }
    }
  }
}

__device__ __forceinline__ void reduce12(const float (&acc)[12][2], float* red, int tid){
  const int w = tid>>6, l2 = (tid&63)*2;
  __syncthreads();
  #pragma unroll
  for (int r=0;r<12;++r){
    red[(u64)(w*12+r)*128 + l2]   = acc[r][0];
    red[(u64)(w*12+r)*128 + l2+1] = acc[r][1];
  }
  __syncthreads();
}

#define AM_ENC 0
#define AM_DEC 1
#define AM_CAT 2

template<int AMODE>
__global__ __launch_bounds__(256)
void gemm_gx(const float* __restrict__ embed,
             u64 a1_f, u64 a2_f,
             const int* __restrict__ ids,
             const float* __restrict__ W,
             const float* __restrict__ bias,
             u64 c_f, int K)
{
  constexpr int TM=128, TN=64, TK=32;
  __shared__ float As[TK][TM+4];
  __shared__ float Ws[TK][TN+4];
  __shared__ int rowid[TM];
  const int t = blockIdx.x;
  const int n0 = blockIdx.y*TN;
  const int tid = threadIdx.x;

  if (AMODE != AM_CAT){
    for (int r=tid; r<TM; r+=256)
      rowid[r] = (AMODE==AM_ENC) ? ids[r*TLEN+t] : ((t==0)?1:ids[r*TLEN+t-1]);
    __syncthreads();
  }

  const int tm = tid>>4, tn = tid&15;
  float acc[8][4];
  #pragma unroll
  for (int i=0;i<8;i++){ acc[i][0]=0.f;acc[i][1]=0.f;acc[i][2]=0.f;acc[i][3]=0.f; }

  for (int k0=0;k0<K;k0+=TK){
    if (AMODE==AM_CAT){
      const int kk = tid>>3, q = tid&7;
      const int kg = k0 + kk;
      const float* src = g_pool + ((kg<HDIM)? (a1_f + ((u64)t*HDIM + kg)*BSZ)
                                            : (a2_f + ((u64)t*HDIM + (kg-HDIM))*BSZ)) + q*16;
      float* d = &As[kk][q*16];
      float4 v0=*(const float4*)(src+0), v1=*(const float4*)(src+4);
      float4 v2=*(const float4*)(src+8), v3=*(const float4*)(src+12);
      *(float4*)(d+0)=v0; *(float4*)(d+4)=v1; *(float4*)(d+8)=v2; *(float4*)(d+12)=v3;
    } else {
      #pragma unroll
      for (int l=tid; l<TM*TK; l+=256){
        int r=l>>5, k=l&31;
        As[k][r] = embed[(u64)rowid[r]*HDIM + k0 + k];
      }
    }
    #pragma unroll
    for (int l=tid; l<TN*TK; l+=256){
      int n=l>>5, k=l&31;
      Ws[k][n] = W[(u64)(n0+n)*K + k0 + k];
    }
    __syncthreads();
    #pragma unroll 8
    for (int kk=0;kk<TK;kk++){
      float4 a0 = *(const float4*)&As[kk][tm*8];
      float4 a1 = *(const float4*)&As[kk][tm*8+4];
      float4 w  = *(const float4*)&Ws[kk][tn*4];
      float av[8]={a0.x,a0.y,a0.z,a0.w,a1.x,a1.y,a1.z,a1.w};
      float wv[4]={w.x,w.y,w.z,w.w};
      #pragma unroll
      for (int i=0;i<8;i++){
        #pragma unroll
        for (int jj=0;jj<4;jj++) acc[i][jj] += av[i]*wv[jj];
      }
    }
    __syncthreads();
  }

  float bv[4];
  #pragma unroll
  for (int jj=0;jj<4;jj++) bv[jj] = bias[n0+tn*4+jj];
  float* C = g_pool + c_f;
  for (int half=0; half<2; ++half){
    if ((tn>>3)==half){
      #pragma unroll
      for (int i=0;i<8;i++)
        #pragma unroll
        for (int jj=0;jj<4;jj++)
          As[(tn&7)*4+jj][tm*8+i] = acc[i][jj]+bv[jj];
    }
    __syncthreads();
    {
      const int nn = tid>>3, q = tid&7;
      float* dst = C + ((u64)t*G3 + n0 + half*32 + nn)*BSZ + q*16;
      const float* srow = &As[nn][q*16];
      float4 v0=*(const float4*)(srow+0), v1=*(const float4*)(srow+4);
      float4 v2=*(const float4*)(srow+8), v3=*(const float4*)(srow+12);
      *(float4*)(dst+0)=v0; *(float4*)(dst+4)=v1; *(float4*)(dst+8)=v2; *(float4*)(dst+12)=v3;
    }
    __syncthreads();
  }
}

// f32-A 12-row GEMM for scans
__device__ __forceinline__ void ggemm12(const u16* __restrict__ wl,
                                        const float* __restrict__ aT,
                                        float (&acc)[12][2], int tid)
{
  const int w = tid>>6, l2 = (tid&63)*2;
  #pragma unroll
  for (int r=0;r<12;++r){ acc[r][0]=0.f; acc[r][1]=0.f; }
  const int k0 = w*128;
  const float* ap = aT + (u64)k0*BSZ + l2;
  const u16* wp = wl + k0*12;
  for (int kb=0; kb<128; kb+=16){
    float2 a[16];
    #pragma unroll
    for (int u=0;u<16;++u) a[u] = *(const float2*)(ap + (u64)(kb+u)*BSZ);
    #pragma unroll
    for (int u=0;u<16;++u){
      const u16* wr = wp + (kb+u)*12;
      #pragma unroll
      for (int r=0;r<12;++r){
        const float wv = b2f(wr[r]);
        acc[r][0] += wv*a[u].x; acc[r][1] += wv*a[u].y;
      }
    }
  }
}

// paired scans: blocks 0..255 = fwd stream A, 256..511 = bwd stream B (independent barriers)
__global__ __launch_bounds__(512)
void scan_pair(u64 gxA, u64 gxB, u64 p0A, u64 p1A, u64 p0B, u64 p1B,
               const float* __restrict__ whhA, const float* __restrict__ whhB,
               const float* __restrict__ bhhA, const float* __restrict__ bhhB,
               const int* __restrict__ lengths, u64 outA, u64 outB)
{
  __shared__ u16 wl[HDIM*12];
  __shared__ float red[8*12*128];
  const int gbid = blockIdx.x, tid = threadIdx.x;
  const int half = gbid >> 8;
  const int bid  = gbid & 255;
  const u64 gx_f = half? gxB : gxA;
  const u64 p0_f = half? p0B : p0A;
  const u64 p1_f = half? p1B : p1A;
  const float* whh = half? whhB : whhA;
  const float* bhh = half? bhhB : bhhA;
  const u64 out_f = half? outB : outA;
  const bool bwd = (half != 0);

  const int j0 = bid*4;
  #pragma unroll
  for (int r=0;r<12;++r){
    const int row = (r>>2)*HDIM + j0 + (r&3);
    for (int k=tid;k<HDIM;k+=512) wl[k*12+r] = f2b(whh[(u64)row*HDIM + k]);
  }
  __syncthreads();

  const int jl = tid>>7, bb = tid&127;
  const int jg = j0 + jl;
  for (int s=0; s<TLEN; ++s){
    const int t = bwd ? (TLEN-1-s) : s;
    const u64 rd = (s&1)? p0_f : p1_f;
    const u64 wr = (s&1)? p1_f : p0_f;
    if (s>0){
      float acc[12][2];
      ggemm12(wl, g_pool + rd, acc, tid);
      reduce12(acc, red, tid);
    }
    const float* gxb = g_pool + gx_f + (u64)t*G3*BSZ;
    {
      const int len = lengths[bb];
      const bool m = (t < len);
      float gh0=0.f, gh1=0.f, gh2=0.f;
      if (s>0){
        #pragma unroll
        for (int w2=0;w2<8;++w2){
          gh0 += red[(u64)(w2*12 + jl)*128 + bb];
          gh1 += red[(u64)(w2*12 + 4 + jl)*128 + bb];
          gh2 += red[(u64)(w2*12 + 8 + jl)*128 + bb];
        }
      }
      const float xr = gxb[(u64)jg*BSZ + bb];
      const float xz = gxb[(u64)(HDIM+jg)*BSZ + bb];
      const float xn = gxb[(u64)(2*HDIM+jg)*BSZ + bb];
      const float hp = (s>0)? g_pool[rd + (u64)jg*BSZ + bb] : 0.f;
      const float r = sigmf(xr + gh0 + bhh[jg]);
      const float z = sigmf(xz + gh1 + bhh[HDIM+jg]);
      const float n = tanhf(xn + r*(gh2 + bhh[2*HDIM+jg]));
      const float hv = (1.f-z)*n + z*hp;
      g_pool[wr + (u64)jg*BSZ + bb] = m ? hv : hp;
      g_pool[out_f + ((u64)t*HDIM + jg)*BSZ + bb] = m ? hv : 0.f;
    }
    grid_sync_h(half);
  }
}

// one-time converters: cw/ow -> bf16, decoder initial states -> bf16
__global__ __launch_bounds__(256)
void conv_w(const float* __restrict__ cw, const float* __restrict__ ow){
  u16* cwb = (u16*)(g_pool + F_CWB);
  u16* owb = (u16*)(g_pool + F_OWB);
  u16* hi0 = (u16*)(g_pool + F_SHI0);
  u16* hi1 = (u16*)(g_pool + F_SHI1);
  const u64 n1 = (u64)HDIM*2*HDIM;
  const u64 n2 = (u64)NTAG*HDIM;
  const u64 n3 = (u64)HDIM*BSZ;
  for (u64 i = (u64)blockIdx.x*256+threadIdx.x; i<n1; i += (u64)gridDim.x*256) cwb[i]=f2b(cw[i]);
  for (u64 i = (u64)blockIdx.x*256+threadIdx.x; i<n2; i += (u64)gridDim.x*256) owb[i]=f2b(ow[i]);
  for (u64 i = (u64)blockIdx.x*256+threadIdx.x; i<n3; i += (u64)gridDim.x*256){
    hi0[i]=f2b(g_pool[F_H0F + i]);
    hi1[i]=f2b(g_pool[F_H0B + i]);
  }
}
__global__ __launch_bounds__(256)
void enc_t(){
  const int t = blockIdx.x, kc = blockIdx.y;
  u16* etb = (u16*)(g_pool + F_ETB);
  for (int it=threadIdx.x; it<128*128; it+=256){
    const int kl = it>>7, b = it&127;
    const int k = kc*128 + kl;
    const u64 idx = ((u64)t*HDIM+k)*BSZ + b;
    etb[(u64)b*(TLEN*HDIM) + (u64)t*HDIM + k] = f2b(g_pool[F_ENC + idx] + g_pool[F_ENC2 + idx]);
  }
}

// persistent decoder: 256 blocks x 512 threads; all states bf16 [k][b]
__global__ __launch_bounds__(512)
void decoder_kernel(const float* __restrict__ whh0, const float* __restrict__ bhh0,
                    const float* __restrict__ wih1, const float* __restrict__ bih1,
                    const float* __restrict__ whh1, const float* __restrict__ bhh1,
                    const float* __restrict__ cb, const float* __restrict__ ob,
                    const int* __restrict__ tag_ids, const int* __restrict__ lengths,
                    float* __restrict__ dout)
{
  __shared__ u16 wl0[HDIM*12];
  __shared__ u16 wl1[HDIM*12];
  __shared__ u16 wl2[HDIM*12];
  __shared__ float red[8*12*128];
  __shared__ float aL[64];
  const int bid = blockIdx.x, tid = threadIdx.x;
  const int j0 = bid*4;
  const int ab = bid>>1, kh2 = bid&1;
  const int w = tid>>6, l2 = (tid&63)*2, l = tid&63;
  const int jl = tid>>7, bb = tid&127;
  const int jg = j0 + jl;

  #pragma unroll
  for (int r=0;r<12;++r){
    const int gr = (r>>2)*HDIM + j0 + (r&3);
    for (int k=tid;k<HDIM;k+=512){
      wl0[k*12+r] = f2b(whh0[(u64)gr*HDIM + k]);
      wl1[k*12+r] = f2b(wih1[(u64)gr*HDIM + k]);
      wl2[k*12+r] = f2b(whh1[(u64)gr*HDIM + k]);
    }
  }
  __syncthreads();

  u16* h1t = (u16*)(g_pool + F_H1T);
  const u16* etb = (const u16*)(g_pool + F_ETB);
  const u16* cwb = (const u16*)(g_pool + F_CWB);
  const u16* owb = (const u16*)(g_pool + F_OWB);
  u16* sctx = (u16*)(g_pool + F_SCTX);
  u16* scc  = (u16*)(g_pool + F_SCC);

  for (int t=0; t<TLEN; ++t){
    const u16* h0c = (const u16*)(g_pool + ((t==0)? F_SHI0 : ((t&1)? F_SH0A : F_SH0B)));
    u16*       h0n = (u16*)(g_pool + ((t&1)? F_SH0B : F_SH0A));
    const u16* h1c = (const u16*)(g_pool + ((t==0)? F_SHI1 : ((t&1)? F_SH1A : F_SH1B)));
    u16*       h1n = (u16*)(g_pool + ((t&1)? F_SH1B : F_SH1A));

    // ---- P1: layer-0 GRU ----
    {
      float acc[12][2];
      ggemm12u(wl0, h0c, acc, tid);
      reduce12(acc, red, tid);
      const float* gxb = g_pool + F_GX + (u64)t*G3*BSZ;
      float gh0=0.f, gh1=0.f, gh2=0.f;
      #pragma unroll
      for (int w2=0;w2<8;++w2){
        gh0 += red[(u64)(w2*12 + jl)*128 + bb];
        gh1 += red[(u64)(w2*12 + 4 + jl)*128 + bb];
        gh2 += red[(u64)(w2*12 + 8 + jl)*128 + bb];
      }
      const float xr = gxb[(u64)jg*BSZ+bb], xz = gxb[(u64)(HDIM+jg)*BSZ+bb], xn = gxb[(u64)(2*HDIM+jg)*BSZ+bb];
      const float hp = b2f(h0c[(u64)jg*BSZ + bb]);
      const float r = sigmf(xr + gh0 + bhh0[jg]);
      const float z = sigmf(xz + gh1 + bhh0[HDIM+jg]);
      const float n = tanhf(xn + r*(gh2 + bhh0[2*HDIM+jg]));
      h0n[(u64)jg*BSZ + bb] = f2b((1.f-z)*n + z*hp);
    }
    grid_sync();   // b1

    // ---- P2: layer-1 GRU (two GEMMs) ----
    {
      float acc[12][2];
      float aX[3], aH[3];
      ggemm12u(wl1, h0n, acc, tid);
      reduce12(acc, red, tid);
      #pragma unroll
      for (int g=0;g<3;++g){
        float s=0.f;
        #pragma unroll
        for (int w2=0;w2<8;++w2) s += red[(u64)(w2*12 + g*4 + jl)*128 + bb];
        aX[g] = s;
      }
      ggemm12u(wl2, h1c, acc, tid);
      reduce12(acc, red, tid);
      #pragma unroll
      for (int g=0;g<3;++g){
        float s=0.f;
        #pragma unroll
        for (int w2=0;w2<8;++w2) s += red[(u64)(w2*12 + g*4 + jl)*128 + bb];
        aH[g] = s;
      }
      const float hp = b2f(h1c[(u64)jg*BSZ + bb]);
      const float r = sigmf(aX[0] + bih1[jg] + aH[0] + bhh1[jg]);
      const float z = sigmf(aX[1] + bih1[HDIM+jg] + aH[1] + bhh1[HDIM+jg]);
      const float n = tanhf(aX[2] + bih1[2*HDIM+jg] + r*(aH[2] + bhh1[2*HDIM+jg]));
      const float hv = (1.f-z)*n + z*hp;
      const u16 hb = f2b(hv);
      h1n[(u64)jg*BSZ + bb] = hb;
      h1t[(u64)bb*HDIM + jg] = hb;
    }
    grid_sync();   // b2

    // ---- P3: score partials (block = (b=ab, k-half=kh2); 8 waves over tp) ----
    {
      const u16* h1r = h1t + (u64)ab*HDIM + kh2*512 + l*8;
      float hv[8];
      #pragma unroll
      for (int u=0;u<8;++u) hv[u] = b2f(h1r[u]);
      for (int tp=w; tp<TLEN; tp+=8){
        const u16* er = etb + (u64)ab*(TLEN*HDIM) + (u64)tp*HDIM + kh2*512 + l*8;
        float s=0.f;
        #pragma unroll
        for (int u=0;u<8;++u) s += hv[u]*b2f(er[u]);
        #pragma unroll
        for (int o=32;o;o>>=1) s += __shfl_xor(s, o);
        if (l==0) g_pool[F_QP + (u64)kh2*TLEN*BSZ + (u64)tp*BSZ + ab] = s;
      }
    }
    grid_sync();   // b3

    // ---- P4: softmax (redundant per pair) + ctx half from etb ----
    {
      if (tid < 64){
        float v = -1e30f;
        if (tid < TLEN)
          v = g_pool[F_QP + (u64)tid*BSZ + ab] + g_pool[F_QP + (u64)(TLEN+tid)*BSZ + ab];
        float mx = v;
        #pragma unroll
        for (int o=32;o;o>>=1) mx = fmaxf(mx, __shfl_xor(mx,o));
        float e = (tid<TLEN)? __expf(v-mx) : 0.f;
        float sm = e;
        #pragma unroll
        for (int o=32;o;o>>=1) sm += __shfl_xor(sm,o);
        if (tid < TLEN) aL[tid] = e/sm;
      }
      __syncthreads();
      {
        const int kk = tid;
        const u16* eb = etb + (u64)ab*(TLEN*HDIM) + kh2*512 + kk;
        float acc = 0.f;
        #pragma unroll 10
        for (int tp=0;tp<TLEN;++tp) acc += aL[tp]*b2f(eb[(u64)tp*HDIM]);
        sctx[(u64)(kh2*512+kk)*BSZ + ab] = f2b(acc);
      }
    }
    grid_sync();   // b4

    // ---- P5: cc (8 waves x K=256 slices; 4 rows each; cross-wave reduce) ----
    {
      const int k0 = w*256;
      const u16* asrc = (k0<1024)? ((const u16*)(g_pool + ((t&1)? F_SH1B : F_SH1A)) + (u64)k0*BSZ)
                                 : (sctx + (u64)(k0-1024)*BSZ);
      const u16* wp0 = cwb + (u64)(j0+0)*2048 + k0;
      const u16* wp1 = cwb + (u64)(j0+1)*2048 + k0;
      const u16* wp2 = cwb + (u64)(j0+2)*2048 + k0;
      const u16* wp3 = cwb + (u64)(j0+3)*2048 + k0;
      float a0[4]={0,0,0,0}, a1v[4]={0,0,0,0};
      for (int kb=0; kb<256; kb+=16){
        unsigned a[16];
        #pragma unroll
        for (int u=0;u<16;++u) a[u] = *(const unsigned*)(asrc + (u64)(kb+u)*BSZ + l2);
        #pragma unroll
        for (int u=0;u<16;++u){
          const float ax = b2f_lo(a[u]), ay = b2f_hi(a[u]);
          const float w0v=b2f(wp0[kb+u]), w1v=b2f(wp1[kb+u]), w2v=b2f(wp2[kb+u]), w3v=b2f(wp3[kb+u]);
          a0[0]+=w0v*ax; a1v[0]+=w0v*ay;
          a0[1]+=w1v*ax; a1v[1]+=w1v*ay;
          a0[2]+=w2v*ax; a1v[2]+=w2v*ay;
          a0[3]+=w3v*ax; a1v[3]+=w3v*ay;
        }
      }
      __syncthreads();
      #pragma unroll
      for (int r=0;r<4;++r){
        red[(u64)(w*4+r)*128 + l2]   = a0[r];
        red[(u64)(w*4+r)*128 + l2+1] = a1v[r];
      }
      __syncthreads();
      {
        const int n2 = j0 + jl;
        float s = cb[n2];
        #pragma unroll
        for (int w2=0;w2<8;++w2) s += red[(u64)(w2*4+jl)*128 + bb];
        scc[(u64)n2*BSZ + bb] = f2b(tanhf(s));
      }
    }
    grid_sync();   // b5

    // ---- P6: logits row v=bid (8-way k-split, bf16 ow + bf16 cc) ----
    {
      const u16* owv = owb + (u64)bid*HDIM + w*128;
      const u16* ccp = scc + (u64)w*128*BSZ;
      float a0=0.f, a1v=0.f;
      for (int kb=0; kb<128; kb+=16){
        unsigned a[16];
        #pragma unroll
        for (int u=0;u<16;++u) a[u] = *(const unsigned*)(ccp + (u64)(kb+u)*BSZ + l2);
        #pragma unroll
        for (int u=0;u<16;++u){
          const float wv = b2f(owv[kb+u]);
          a0 += wv*b2f_lo(a[u]); a1v += wv*b2f_hi(a[u]);
        }
      }
      __syncthreads();
      red[(u64)w*128 + l2]   = a0;
      red[(u64)w*128 + l2+1] = a1v;
      __syncthreads();
      if (tid < 128){
        float lg = ob[bid];
        #pragma unroll
        for (int w2=0;w2<8;++w2) lg += red[(u64)w2*128 + tid];
        g_pool[F_LG + (u64)bid*BSZ + tid] = lg;
      }
    }
    grid_sync();   // b6

    // ---- P7: per-b softmax + nll ----
    {
      float* lgs = red;
      float* rp  = red + 256;
      const bool act = (bid < BSZ) && (tid < 256);
      float lg = 0.f;
      if (act){
        lg = g_pool[F_LG + (u64)tid*BSZ + bid];
        lgs[tid] = lg; rp[tid] = lg;
      }
      __syncthreads();
      for (int o=128;o;o>>=1){ if (bid<BSZ && tid<o) rp[tid]=fmaxf(rp[tid],rp[tid+o]); __syncthreads(); }
      const float mx = (bid<BSZ)? rp[0] : 0.f;
      __syncthreads();
      if (act) rp[tid] = __expf(lg-mx);
      __syncthreads();
      for (int o=128;o;o>>=1){ if (bid<BSZ && tid<o) rp[tid]+=rp[tid+o]; __syncthreads(); }
      if (act){
        const float lse = mx + __logf(rp[0]);
        dout[((u64)bid*TLEN + t)*NTAG + tid] = lg;
        if (tid==0){
          const int tag = tag_ids[bid*TLEN + t];
          g_pool[F_NLL + (u64)t*BSZ + bid] = lse - lgs[tag];
        }
      }
    }
  }
  grid_sync();
  // ---- loss ----
  if (bid == 0){
    float ssum = 0.f;
    for (int i=tid; i<TLEN*BSZ; i+=512){
      const int tt = i>>7, b = i&127;
      if (tt < lengths[b]) ssum += g_pool[F_NLL + i];
    }
    red[tid] = ssum; __syncthreads();
    for (int o=256;o;o>>=1){ if (tid<o) red[tid]+=red[tid+o]; __syncthreads(); }
    if (tid==0){
      int den=0;
      for (int b=0;b<BSZ;b++) den += lengths[b];
      dout[(u64)BSZ*TLEN*NTAG] = red[0]/(float)den;
    }
  }
}

extern "C" void kernel_launch(void* const* d_in, const int* in_sizes, int n_in,
                              void* d_out, int out_size, void* d_ws, size_t ws_size,
                              hipStream_t stream)
{
  const float* enc_embed = (const float*)d_in[0];
  const float* e0_wih = (const float*)d_in[1];
  const float* e0_whh = (const float*)d_in[2];
  const float* e0_bih = (const float*)d_in[3];
  const float* e0_bhh = (const float*)d_in[4];
  const float* e1_wih = (const float*)d_in[5];
  const float* e1_whh = (const float*)d_in[6];
  const float* e1_bih = (const float*)d_in[7];
  const float* e1_bhh = (const float*)d_in[8];
  const float* dec_embed = (const float*)d_in[9];
  const float* d_wih = (const float*)d_in[10];
  const float* d_whh = (const float*)d_in[11];
  const float* d_bih = (const float*)d_in[12];
  const float* d_bhh = (const float*)d_in[13];
  const float* concat_w = (const float*)d_in[14];
  const float* concat_b = (const float*)d_in[15];
  const float* out_w = (const float*)d_in[16];
  const float* out_b = (const float*)d_in[17];
  const int* input_ids = (const int*)d_in[18];
  const int* tag_ids  = (const int*)d_in[19];
  const int* lengths  = (const int*)d_in[20];
  float* dout = (float*)d_out;

  const dim3 gxg(TLEN, G3/64);

  // encoder layer 0: both directions' gx, then paired concurrent scans
  gemm_gx<AM_ENC><<<gxg,256,0,stream>>>(enc_embed,0,0,input_ids,e0_wih,e0_bih,F_GX,HDIM);
  gemm_gx<AM_ENC><<<gxg,256,0,stream>>>(enc_embed,0,0,input_ids,
                                        e0_wih+(u64)G3*HDIM, e0_bih+G3, F_GXB, HDIM);
  scan_pair<<<2*NBLK,512,0,stream>>>(F_GX, F_GXB, F_T0, F_H0F, F_T1, F_H0B,
                                     e0_whh, e0_whh+(u64)G3*HDIM, e0_bhh, e0_bhh+G3,
                                     lengths, F_OF0, F_OB0);
  // encoder layer 1
  gemm_gx<AM_CAT><<<gxg,256,0,stream>>>(nullptr, F_OF0, F_OB0, nullptr,
                                        e1_wih, e1_bih, F_GX, 2*HDIM);
  gemm_gx<AM_CAT><<<gxg,256,0,stream>>>(nullptr, F_OF0, F_OB0, nullptr,
                                        e1_wih+(u64)G3*2*HDIM, e1_bih+G3, F_GXB, 2*HDIM);
  scan_pair<<<2*NBLK,512,0,stream>>>(F_GX, F_GXB, F_T0, F_X0, F_T1, F_X1,
                                     e1_whh, e1_whh+(u64)G3*HDIM, e1_bhh, e1_bhh+G3,
                                     lengths, F_ENC, F_ENC2);
  // decoder
  gemm_gx<AM_DEC><<<gxg,256,0,stream>>>(dec_embed,0,0,tag_ids, d_wih, d_bih, F_GX, HDIM);
  conv_w<<<256,256,0,stream>>>(concat_w, out_w);
  enc_t<<<dim3(TLEN,8),256,0,stream>>>();
  decoder_kernel<<<NBLK,512,0,stream>>>(d_whh, d_bhh,
                                        d_wih+(u64)G3*HDIM, d_bih+G3,
                                        d_whh+(u64)G3*HDIM, d_bhh+G3,
                                        concat_b, out_b,
                                        tag_ids, lengths, dout);
}